// Round 1
// baseline (576.193 us; speedup 1.0000x reference)
//
#include <hip/hip_runtime.h>
#include <math.h>

#define Bn 32
#define Nn 2048
#define Cc 256
#define Sn 128
#define KK 16
#define CIN 259
#define H 128
#define OUTC 79
#define ODIM 124

__device__ __constant__ float MEANF[30] = {
    0.76584f, 1.398258f, 0.472728f,
    2.114256f, 1.6203f, 0.927272f,
    0.404671f, 1.071108f, 1.688889f,
    0.591958f, 0.552978f, 0.827272f,
    0.69519f, 1.346299f, 0.736364f,
    0.528526f, 1.002642f, 1.172878f,
    0.500618f, 0.632163f, 0.683424f,
    0.923508f, 1.867419f, 0.845495f,
    0.791118f, 1.279516f, 0.718182f,
    0.699104f, 0.454178f, 0.75625f};

// ---------------- FPS: one block per batch ----------------
__global__ __launch_bounds__(256) void fps_kernel(const float* __restrict__ xyz,
                                                  int* __restrict__ fps_idx,
                                                  float* __restrict__ new_xyz) {
#pragma clang fp contract(off)
    const int b = blockIdx.x;
    const int t = threadIdx.x;
    __shared__ float xs[Nn * 3];
    __shared__ float red_v[4];
    __shared__ int red_i[4];
    __shared__ int s_last;

    for (int i = t; i < Nn * 3; i += 256) xs[i] = xyz[b * Nn * 3 + i];
    __syncthreads();

    float mind[8];
#pragma unroll
    for (int j = 0; j < 8; j++) mind[j] = 1e10f;

    int last = 0;
    for (int it = 0; it < Sn; ++it) {
        if (t == 0) {
            fps_idx[b * Sn + it] = last;
            new_xyz[(b * Sn + it) * 3 + 0] = xs[last * 3 + 0];
            new_xyz[(b * Sn + it) * 3 + 1] = xs[last * 3 + 1];
            new_xyz[(b * Sn + it) * 3 + 2] = xs[last * 3 + 2];
        }
        const float lx = xs[last * 3 + 0];
        const float ly = xs[last * 3 + 1];
        const float lz = xs[last * 3 + 2];
        float bestv = -1.0f;
        int besti = 0x3fffffff;
#pragma unroll
        for (int j = 0; j < 8; j++) {
            const int p = t + j * 256;
            const float dx = xs[p * 3 + 0] - lx;
            const float dy = xs[p * 3 + 1] - ly;
            const float dz = xs[p * 3 + 2] - lz;
            const float dx2 = dx * dx;
            const float dy2 = dy * dy;
            const float dz2 = dz * dz;
            const float s01 = dx2 + dy2;
            const float d = s01 + dz2;
            float m = mind[j];
            m = fminf(m, d);
            mind[j] = m;
            if (m > bestv) { bestv = m; besti = p; }  // ascending p: strict > keeps first occurrence
        }
        // wave reduce (64 lanes), max value, tie -> min index
        for (int off = 32; off > 0; off >>= 1) {
            const float ov = __shfl_down(bestv, off);
            const int oi = __shfl_down(besti, off);
            if (ov > bestv || (ov == bestv && oi < besti)) { bestv = ov; besti = oi; }
        }
        const int wave = t >> 6;
        if ((t & 63) == 0) { red_v[wave] = bestv; red_i[wave] = besti; }
        __syncthreads();
        if (t == 0) {
            for (int w = 1; w < 4; w++) {
                if (red_v[w] > bestv || (red_v[w] == bestv && red_i[w] < besti)) {
                    bestv = red_v[w];
                    besti = red_i[w];
                }
            }
            s_last = besti;
        }
        __syncthreads();
        last = s_last;
    }
}

// ---------------- transpose features (B,C,N) -> (B,N,C) ----------------
__global__ __launch_bounds__(256) void transpose_kernel(const float* __restrict__ f,
                                                        float* __restrict__ fT) {
    __shared__ float tile[32][33];
    const int b = blockIdx.z;
    const int n0 = blockIdx.x * 32;
    const int c0 = blockIdx.y * 32;
    const int tx = threadIdx.x & 31;
    const int ty = threadIdx.x >> 5;  // 0..7
    for (int i = ty; i < 32; i += 8)
        tile[i][tx] = f[((size_t)b * Cc + (c0 + i)) * Nn + n0 + tx];
    __syncthreads();
    for (int i = ty; i < 32; i += 8)
        fT[((size_t)b * Nn + (n0 + i)) * Cc + c0 + tx] = tile[tx][i];
}

// ---------------- ball query: one wave per (b,s) ----------------
__global__ __launch_bounds__(64) void ballq_kernel(const float* __restrict__ xyz,
                                                   const float* __restrict__ new_xyz,
                                                   int* __restrict__ bidx) {
#pragma clang fp contract(off)
    const int bs = blockIdx.x;
    const int b = bs >> 7;  // /Sn
    const int lane = threadIdx.x;
    const float cx = new_xyz[bs * 3 + 0];
    const float cy = new_xyz[bs * 3 + 1];
    const float cz = new_xyz[bs * 3 + 2];
    const float rr = 0.09f;
    __shared__ int buf[16];

    int base = 0;
    for (int c0 = 0; c0 < Nn; c0 += 64) {
        const int p = c0 + lane;
        const float dx = xyz[((size_t)b * Nn + p) * 3 + 0] - cx;
        const float dy = xyz[((size_t)b * Nn + p) * 3 + 1] - cy;
        const float dz = xyz[((size_t)b * Nn + p) * 3 + 2] - cz;
        const float dx2 = dx * dx;
        const float dy2 = dy * dy;
        const float dz2 = dz * dz;
        const float s01 = dx2 + dy2;
        const float d2 = s01 + dz2;
        const bool q = d2 < rr;
        const unsigned long long mask = __ballot(q);
        const int prefix = __popcll(mask & ((1ull << lane) - 1ull));
        const int slot = base + prefix;
        if (q && slot < KK) buf[slot] = p;
        base += __popcll(mask);
        if (base >= KK) break;
    }
    __syncthreads();
    const int cnt = base < KK ? base : KK;
    if (lane < KK) {
        int v;
        if (cnt == 0) v = 0;  // cannot happen: center is in set
        else v = (lane < cnt) ? buf[lane] : buf[0];
        bidx[bs * KK + lane] = v;
    }
}

// ---------------- grouped MLP (259->128->128->128) + maxpool over 16 ----------------
__global__ __launch_bounds__(128) void groupmlp_kernel(
    const float* __restrict__ xyz, const float* __restrict__ featT,
    const float* __restrict__ new_xyz, const int* __restrict__ bidx,
    const float* __restrict__ w0, const float* __restrict__ bb0,
    const float* __restrict__ g0, const float* __restrict__ be0,
    const float* __restrict__ m0, const float* __restrict__ v0,
    const float* __restrict__ w1, const float* __restrict__ bb1,
    const float* __restrict__ g1, const float* __restrict__ be1,
    const float* __restrict__ m1, const float* __restrict__ v1,
    const float* __restrict__ w2, const float* __restrict__ bb2,
    const float* __restrict__ g2, const float* __restrict__ be2,
    const float* __restrict__ m2, const float* __restrict__ v2,
    float* __restrict__ pooled) {
    const int bs = blockIdx.x;
    const int b = bs >> 7;
    const int t = threadIdx.x;  // 0..127, output channel

    __shared__ __align__(16) float xin[KK][260];   // [k][0:3]=rel xyz, [k][3:259]=features
    __shared__ __align__(16) float ybuf[KK][128];
    __shared__ int sidx[KK];
    __shared__ float ctr[3];

    if (t < KK) sidx[t] = bidx[bs * KK + t];
    if (t < 3) ctr[t] = new_xyz[bs * 3 + t];
    __syncthreads();

#pragma unroll 4
    for (int k = 0; k < KK; k++) {
        const float* src = featT + ((size_t)b * Nn + sidx[k]) * Cc;
        xin[k][3 + t] = src[t];
        xin[k][3 + 128 + t] = src[128 + t];
    }
    if (t < KK) {
        const int p = sidx[t];
        xin[t][0] = (xyz[((size_t)b * Nn + p) * 3 + 0] - ctr[0]) / 0.3f;
        xin[t][1] = (xyz[((size_t)b * Nn + p) * 3 + 1] - ctr[1]) / 0.3f;
        xin[t][2] = (xyz[((size_t)b * Nn + p) * 3 + 2] - ctr[2]) / 0.3f;
        xin[t][259] = 0.0f;
    }
    // BN folds
    const float sc1 = g0[t] / sqrtf(v0[t] + 1e-5f);
    const float bi1 = (bb0[t] - m0[t]) * sc1 + be0[t];
    const float sc2 = g1[t] / sqrtf(v1[t] + 1e-5f);
    const float bi2 = (bb1[t] - m1[t]) * sc2 + be1[t];
    const float sc3 = g2[t] / sqrtf(v2[t] + 1e-5f);
    const float bi3 = (bb2[t] - m2[t]) * sc3 + be2[t];
    __syncthreads();

    float acc[KK];
    // ---- layer 1: K = 259 ----
#pragma unroll
    for (int k = 0; k < KK; k++) acc[k] = 0.0f;
    for (int i4 = 0; i4 < 64; i4++) {
        const int i = i4 * 4;
        const float wv0 = w0[(i + 0) * H + t];
        const float wv1 = w0[(i + 1) * H + t];
        const float wv2 = w0[(i + 2) * H + t];
        const float wv3 = w0[(i + 3) * H + t];
#pragma unroll
        for (int k = 0; k < KK; k++) {
            const float4 xv = *reinterpret_cast<const float4*>(&xin[k][i]);
            acc[k] += xv.x * wv0 + xv.y * wv1 + xv.z * wv2 + xv.w * wv3;
        }
    }
    {
        const float wv0 = w0[256 * H + t];
        const float wv1 = w0[257 * H + t];
        const float wv2 = w0[258 * H + t];
#pragma unroll
        for (int k = 0; k < KK; k++)
            acc[k] += xin[k][256] * wv0 + xin[k][257] * wv1 + xin[k][258] * wv2;
    }
#pragma unroll
    for (int k = 0; k < KK; k++) ybuf[k][t] = fmaxf(acc[k] * sc1 + bi1, 0.0f);
    __syncthreads();

    // ---- layer 2: K = 128, read ybuf, write into xin rows ----
#pragma unroll
    for (int k = 0; k < KK; k++) acc[k] = 0.0f;
    for (int i4 = 0; i4 < 32; i4++) {
        const int i = i4 * 4;
        const float wv0 = w1[(i + 0) * H + t];
        const float wv1 = w1[(i + 1) * H + t];
        const float wv2 = w1[(i + 2) * H + t];
        const float wv3 = w1[(i + 3) * H + t];
#pragma unroll
        for (int k = 0; k < KK; k++) {
            const float4 xv = *reinterpret_cast<const float4*>(&ybuf[k][i]);
            acc[k] += xv.x * wv0 + xv.y * wv1 + xv.z * wv2 + xv.w * wv3;
        }
    }
    __syncthreads();  // everyone done reading xin (layer-1 inputs no longer needed)
#pragma unroll
    for (int k = 0; k < KK; k++) xin[k][t] = fmaxf(acc[k] * sc2 + bi2, 0.0f);
    __syncthreads();

    // ---- layer 3: K = 128, read xin rows, relu + max-pool over k ----
#pragma unroll
    for (int k = 0; k < KK; k++) acc[k] = 0.0f;
    for (int i4 = 0; i4 < 32; i4++) {
        const int i = i4 * 4;
        const float wv0 = w2[(i + 0) * H + t];
        const float wv1 = w2[(i + 1) * H + t];
        const float wv2 = w2[(i + 2) * H + t];
        const float wv3 = w2[(i + 3) * H + t];
#pragma unroll
        for (int k = 0; k < KK; k++) {
            const float4 xv = *reinterpret_cast<const float4*>(&xin[k][i]);
            acc[k] += xv.x * wv0 + xv.y * wv1 + xv.z * wv2 + xv.w * wv3;
        }
    }
    float vmax = -1e30f;
#pragma unroll
    for (int k = 0; k < KK; k++) vmax = fmaxf(vmax, fmaxf(acc[k] * sc3 + bi3, 0.0f));
    pooled[(size_t)bs * H + t] = vmax;
}

// ---------------- FC head (128->128->128->79) + decode ----------------
__global__ __launch_bounds__(128) void head_kernel(
    const float* __restrict__ pooled, const float* __restrict__ new_xyz,
    const float* __restrict__ c1w, const float* __restrict__ c1b,
    const float* __restrict__ g3, const float* __restrict__ be3,
    const float* __restrict__ m3, const float* __restrict__ v3,
    const float* __restrict__ c2w, const float* __restrict__ c2b,
    const float* __restrict__ g4, const float* __restrict__ be4,
    const float* __restrict__ m4, const float* __restrict__ v4,
    const float* __restrict__ c3w, const float* __restrict__ c3b,
    float* __restrict__ out) {
    const int bs = blockIdx.x;
    const int t = threadIdx.x;
    __shared__ __align__(16) float y0[128];
    __shared__ __align__(16) float y1[128];
    __shared__ __align__(16) float y2[128];
    __shared__ float net[OUTC];

    y0[t] = pooled[(size_t)bs * H + t];
    const float sA = g3[t] / sqrtf(v3[t] + 1e-5f);
    const float bA = (c1b[t] - m3[t]) * sA + be3[t];
    const float sB = g4[t] / sqrtf(v4[t] + 1e-5f);
    const float bB = (c2b[t] - m4[t]) * sB + be4[t];
    __syncthreads();

    float acc = 0.0f;
    for (int i4 = 0; i4 < 32; i4++) {
        const int i = i4 * 4;
        const float4 xv = *reinterpret_cast<const float4*>(&y0[i]);
        acc += xv.x * c1w[(i + 0) * H + t] + xv.y * c1w[(i + 1) * H + t] +
               xv.z * c1w[(i + 2) * H + t] + xv.w * c1w[(i + 3) * H + t];
    }
    y1[t] = fmaxf(acc * sA + bA, 0.0f);
    __syncthreads();

    acc = 0.0f;
    for (int i4 = 0; i4 < 32; i4++) {
        const int i = i4 * 4;
        const float4 xv = *reinterpret_cast<const float4*>(&y1[i]);
        acc += xv.x * c2w[(i + 0) * H + t] + xv.y * c2w[(i + 1) * H + t] +
               xv.z * c2w[(i + 2) * H + t] + xv.w * c2w[(i + 3) * H + t];
    }
    y2[t] = fmaxf(acc * sB + bB, 0.0f);
    __syncthreads();

    if (t < OUTC) {
        float a = c3b[t];
        for (int i4 = 0; i4 < 32; i4++) {
            const int i = i4 * 4;
            const float4 xv = *reinterpret_cast<const float4*>(&y2[i]);
            a += xv.x * c3w[(i + 0) * OUTC + t] + xv.y * c3w[(i + 1) * OUTC + t] +
                 xv.z * c3w[(i + 2) * OUTC + t] + xv.w * c3w[(i + 3) * OUTC + t];
        }
        net[t] = a;
    }
    __syncthreads();

    if (t < ODIM) {
        const float* nz = new_xyz + (size_t)bs * 3;
        float val;
        if (t < 3) val = nz[t];
        else if (t < 5) val = net[t - 3];                       // obj
        else if (t < 8) val = nz[t - 5] + net[2 + (t - 5)];     // ctr
        else if (t < 20) val = net[5 + (t - 8)];                // hs
        else if (t < 32) val = net[17 + (t - 20)];              // hrn
        else if (t < 44) val = net[17 + (t - 32)] * (float)(3.14159265358979323846 / 12.0);  // hr
        else if (t < 54) val = net[29 + (t - 44)];              // ss
        else if (t < 84) val = net[39 + (t - 54)];              // srn
        else if (t < 114) val = net[39 + (t - 84)] * MEANF[t - 84];  // sr
        else val = net[69 + (t - 114)];                         // sem
        out[(size_t)bs * ODIM + t] = val;
    }
}

extern "C" void kernel_launch(void* const* d_in, const int* in_sizes, int n_in,
                              void* d_out, int out_size, void* d_ws, size_t ws_size,
                              hipStream_t stream) {
    (void)in_sizes; (void)n_in; (void)out_size; (void)ws_size;
    const float* xyz = (const float*)d_in[0];
    const float* features = (const float*)d_in[1];
    const float* w0 = (const float*)d_in[2];
    const float* bb0 = (const float*)d_in[3];
    const float* g0 = (const float*)d_in[4];
    const float* be0 = (const float*)d_in[5];
    const float* m0 = (const float*)d_in[6];
    const float* v0 = (const float*)d_in[7];
    const float* w1 = (const float*)d_in[8];
    const float* bb1 = (const float*)d_in[9];
    const float* g1 = (const float*)d_in[10];
    const float* be1 = (const float*)d_in[11];
    const float* m1 = (const float*)d_in[12];
    const float* v1 = (const float*)d_in[13];
    const float* w2 = (const float*)d_in[14];
    const float* bb2 = (const float*)d_in[15];
    const float* g2 = (const float*)d_in[16];
    const float* be2 = (const float*)d_in[17];
    const float* m2 = (const float*)d_in[18];
    const float* v2 = (const float*)d_in[19];
    const float* c1w = (const float*)d_in[20];
    const float* c1b = (const float*)d_in[21];
    const float* g3 = (const float*)d_in[22];
    const float* be3 = (const float*)d_in[23];
    const float* m3 = (const float*)d_in[24];
    const float* v3 = (const float*)d_in[25];
    const float* c2w = (const float*)d_in[26];
    const float* c2b = (const float*)d_in[27];
    const float* g4 = (const float*)d_in[28];
    const float* be4 = (const float*)d_in[29];
    const float* m4 = (const float*)d_in[30];
    const float* v4 = (const float*)d_in[31];
    const float* c3w = (const float*)d_in[32];
    const float* c3b = (const float*)d_in[33];
    float* out = (float*)d_out;

    char* ws = (char*)d_ws;
    int* fps_idx = (int*)ws;                                    // 32*128 ints
    float* nxyz = (float*)(ws + (size_t)4096 * 4);              // 32*128*3 floats
    int* bidx = (int*)(ws + (size_t)(4096 + 12288) * 4);        // 32*128*16 ints
    float* featT = (float*)(ws + (size_t)(4096 + 12288 + 65536) * 4);  // 32*2048*256 floats
    float* pooled = featT + (size_t)Bn * Nn * Cc;               // 32*128*128 floats

    hipLaunchKernelGGL(fps_kernel, dim3(Bn), dim3(256), 0, stream, xyz, fps_idx, nxyz);
    hipLaunchKernelGGL(transpose_kernel, dim3(Nn / 32, Cc / 32, Bn), dim3(256), 0, stream,
                       features, featT);
    hipLaunchKernelGGL(ballq_kernel, dim3(Bn * Sn), dim3(64), 0, stream, xyz, nxyz, bidx);
    hipLaunchKernelGGL(groupmlp_kernel, dim3(Bn * Sn), dim3(128), 0, stream,
                       xyz, featT, nxyz, bidx,
                       w0, bb0, g0, be0, m0, v0,
                       w1, bb1, g1, be1, m1, v1,
                       w2, bb2, g2, be2, m2, v2, pooled);
    hipLaunchKernelGGL(head_kernel, dim3(Bn * Sn), dim3(128), 0, stream, pooled, nxyz,
                       c1w, c1b, g3, be3, m3, v3,
                       c2w, c2b, g4, be4, m4, v4,
                       c3w, c3b, out);
}

// Round 2
// 414.730 us; speedup vs baseline: 1.3893x; 1.3893x over previous
//
#include <hip/hip_runtime.h>
#include <hip/hip_bf16.h>
#include <math.h>

#define Bn 32
#define Nn 2048
#define Cc 256
#define Sn 128
#define KK 16
#define H 128
#define OUTC 79
#define ODIM 124
#define KP1 288  // layer-1 K padded: 256 features + 3 xyz + 29 zeros

typedef __attribute__((ext_vector_type(8))) short short8;
typedef __attribute__((ext_vector_type(4))) float f32x4;

__device__ __constant__ float MEANF[30] = {
    0.76584f, 1.398258f, 0.472728f,
    2.114256f, 1.6203f, 0.927272f,
    0.404671f, 1.071108f, 1.688889f,
    0.591958f, 0.552978f, 0.827272f,
    0.69519f, 1.346299f, 0.736364f,
    0.528526f, 1.002642f, 1.172878f,
    0.500618f, 0.632163f, 0.683424f,
    0.923508f, 1.867419f, 0.845495f,
    0.791118f, 1.279516f, 0.718182f,
    0.699104f, 0.454178f, 0.75625f};

__device__ __forceinline__ unsigned short f2bf(float f) {
    __hip_bfloat16 h = __float2bfloat16(f);
    return *reinterpret_cast<unsigned short*>(&h);
}

// ---------------- FPS: one block per batch ----------------
__global__ __launch_bounds__(256) void fps_kernel(const float* __restrict__ xyz,
                                                  int* __restrict__ fps_idx,
                                                  float* __restrict__ new_xyz) {
#pragma clang fp contract(off)
    const int b = blockIdx.x;
    const int t = threadIdx.x;
    __shared__ float xs[Nn * 3];
    __shared__ float red_v[4];
    __shared__ int red_i[4];
    __shared__ int s_last;

    for (int i = t; i < Nn * 3; i += 256) xs[i] = xyz[b * Nn * 3 + i];
    __syncthreads();

    float mind[8];
#pragma unroll
    for (int j = 0; j < 8; j++) mind[j] = 1e10f;

    int last = 0;
    for (int it = 0; it < Sn; ++it) {
        if (t == 0) {
            fps_idx[b * Sn + it] = last;
            new_xyz[(b * Sn + it) * 3 + 0] = xs[last * 3 + 0];
            new_xyz[(b * Sn + it) * 3 + 1] = xs[last * 3 + 1];
            new_xyz[(b * Sn + it) * 3 + 2] = xs[last * 3 + 2];
        }
        const float lx = xs[last * 3 + 0];
        const float ly = xs[last * 3 + 1];
        const float lz = xs[last * 3 + 2];
        float bestv = -1.0f;
        int besti = 0x3fffffff;
#pragma unroll
        for (int j = 0; j < 8; j++) {
            const int p = t + j * 256;
            const float dx = xs[p * 3 + 0] - lx;
            const float dy = xs[p * 3 + 1] - ly;
            const float dz = xs[p * 3 + 2] - lz;
            const float dx2 = dx * dx;
            const float dy2 = dy * dy;
            const float dz2 = dz * dz;
            const float s01 = dx2 + dy2;
            const float d = s01 + dz2;
            float m = mind[j];
            m = fminf(m, d);
            mind[j] = m;
            if (m > bestv) { bestv = m; besti = p; }
        }
        for (int off = 32; off > 0; off >>= 1) {
            const float ov = __shfl_down(bestv, off);
            const int oi = __shfl_down(besti, off);
            if (ov > bestv || (ov == bestv && oi < besti)) { bestv = ov; besti = oi; }
        }
        const int wave = t >> 6;
        if ((t & 63) == 0) { red_v[wave] = bestv; red_i[wave] = besti; }
        __syncthreads();
        if (t == 0) {
            for (int w = 1; w < 4; w++) {
                if (red_v[w] > bestv || (red_v[w] == bestv && red_i[w] < besti)) {
                    bestv = red_v[w];
                    besti = red_i[w];
                }
            }
            s_last = besti;
        }
        __syncthreads();
        last = s_last;
    }
}

// ---------------- transpose features (B,C,N) fp32 -> (B,N,C) bf16 ----------------
__global__ __launch_bounds__(256) void transpose_bf16_kernel(const float* __restrict__ f,
                                                             unsigned short* __restrict__ fT) {
    __shared__ float tile[64][33];
    const int b = blockIdx.z;
    const int n0 = blockIdx.x * 32;
    const int c0 = blockIdx.y * 64;
    const int tx = threadIdx.x & 31;
    const int ty = threadIdx.x >> 5;  // 0..7
    for (int i = ty; i < 64; i += 8)
        tile[i][tx] = f[((size_t)b * Cc + (c0 + i)) * Nn + n0 + tx];
    __syncthreads();
    // store phase: thread t handles channel pair cp=2*tx at rows n = ty, ty+8, ...
    for (int n = ty; n < 32; n += 8) {
        const float lo = tile[tx * 2 + 0][n];
        const float hi = tile[tx * 2 + 1][n];
        const unsigned int v = (unsigned int)f2bf(lo) | ((unsigned int)f2bf(hi) << 16);
        *reinterpret_cast<unsigned int*>(&fT[((size_t)b * Nn + (n0 + n)) * Cc + c0 + tx * 2]) = v;
    }
}

// ---------------- ball query: one wave per (b,s) ----------------
__global__ __launch_bounds__(64) void ballq_kernel(const float* __restrict__ xyz,
                                                   const float* __restrict__ new_xyz,
                                                   int* __restrict__ bidx) {
#pragma clang fp contract(off)
    const int bs = blockIdx.x;
    const int b = bs >> 7;
    const int lane = threadIdx.x;
    const float cx = new_xyz[bs * 3 + 0];
    const float cy = new_xyz[bs * 3 + 1];
    const float cz = new_xyz[bs * 3 + 2];
    const float rr = 0.09f;
    __shared__ int buf[16];

    int base = 0;
    for (int c0 = 0; c0 < Nn; c0 += 64) {
        const int p = c0 + lane;
        const float dx = xyz[((size_t)b * Nn + p) * 3 + 0] - cx;
        const float dy = xyz[((size_t)b * Nn + p) * 3 + 1] - cy;
        const float dz = xyz[((size_t)b * Nn + p) * 3 + 2] - cz;
        const float dx2 = dx * dx;
        const float dy2 = dy * dy;
        const float dz2 = dz * dz;
        const float s01 = dx2 + dy2;
        const float d2 = s01 + dz2;
        const bool q = d2 < rr;
        const unsigned long long mask = __ballot(q);
        const int prefix = __popcll(mask & ((1ull << lane) - 1ull));
        const int slot = base + prefix;
        if (q && slot < KK) buf[slot] = p;
        base += __popcll(mask);
        if (base >= KK) break;
    }
    __syncthreads();
    const int cnt = base < KK ? base : KK;
    if (lane < KK) {
        int v;
        if (cnt == 0) v = 0;
        else v = (lane < cnt) ? buf[lane] : buf[0];
        bidx[bs * KK + lane] = v;
    }
}

// ---------------- prep: fold BN, transpose+pad weights to bf16 Wt[n][k] ----------------
__global__ __launch_bounds__(256) void prep_kernel(
    const float* __restrict__ w0, const float* __restrict__ bb0,
    const float* __restrict__ g0, const float* __restrict__ be0,
    const float* __restrict__ m0, const float* __restrict__ v0,
    const float* __restrict__ w1, const float* __restrict__ bb1,
    const float* __restrict__ g1, const float* __restrict__ be1,
    const float* __restrict__ m1, const float* __restrict__ v1,
    const float* __restrict__ w2, const float* __restrict__ bb2,
    const float* __restrict__ g2, const float* __restrict__ be2,
    const float* __restrict__ m2, const float* __restrict__ v2,
    unsigned short* __restrict__ Wt0, unsigned short* __restrict__ Wt1,
    unsigned short* __restrict__ Wt2, float* __restrict__ scbi) {
    const int idx = blockIdx.x * 256 + threadIdx.x;
    // Wt0: [128][288]; k<256 -> feature row (3+k); k in 256..258 -> xyz row (k-256); else 0
    if (idx < 128 * KP1) {
        const int n = idx / KP1;
        const int k = idx - n * KP1;
        float v = 0.0f;
        if (k < 256) v = w0[(3 + k) * H + n];
        else if (k < 259) v = w0[(k - 256) * H + n];
        Wt0[idx] = f2bf(v);
    }
    if (idx < 128 * 128) {
        const int n = idx >> 7;
        const int k = idx & 127;
        Wt1[idx] = f2bf(w1[k * H + n]);
        Wt2[idx] = f2bf(w2[k * H + n]);
    }
    if (idx < 128) {
        const float sc1 = g0[idx] / sqrtf(v0[idx] + 1e-5f);
        scbi[0 * 128 + idx] = sc1;
        scbi[1 * 128 + idx] = (bb0[idx] - m0[idx]) * sc1 + be0[idx];
        const float sc2 = g1[idx] / sqrtf(v1[idx] + 1e-5f);
        scbi[2 * 128 + idx] = sc2;
        scbi[3 * 128 + idx] = (bb1[idx] - m1[idx]) * sc2 + be1[idx];
        const float sc3 = g2[idx] / sqrtf(v2[idx] + 1e-5f);
        scbi[4 * 128 + idx] = sc3;
        scbi[5 * 128 + idx] = (bb2[idx] - m2[idx]) * sc3 + be2[idx];
    }
}

// ---------------- grouped MLP via MFMA: one wave per (b,s) group ----------------
// Per wave: C(16x128) = X(16xK) @ W(Kx128), 3 layers, then maxpool over the 16 rows.
// A-frag layout: A[m=lane&15][k=quad*8+j] (16B/lane); B-frag: B[k=quad*8+j][n=lane&15]
// from Wt[n][k] row-major (16B/lane, quads of same n coalesce to 64B).
// C/D layout: n=lane&15, m=quad*4+reg.
#define YSTR 136  // LDS row stride in bf16 units (272B = 17*16B, 16B-aligned)
__global__ __launch_bounds__(256) void groupmlp_mfma_kernel(
    const float* __restrict__ xyz, const unsigned short* __restrict__ featT,
    const float* __restrict__ new_xyz, const int* __restrict__ bidx,
    const unsigned short* __restrict__ Wt0, const unsigned short* __restrict__ Wt1,
    const unsigned short* __restrict__ Wt2, const float* __restrict__ scbi,
    float* __restrict__ pooled) {
    const int wv = threadIdx.x >> 6;
    const int lane = threadIdx.x & 63;
    const int bs = blockIdx.x * 4 + wv;
    const int b = bs >> 7;
    const int mrow = lane & 15;
    const int quad = lane >> 4;

    __shared__ unsigned short ylds_all[4][16 * YSTR];
    unsigned short* ylds = &ylds_all[wv][0];

    // this lane's sample point (row m of A)
    const int p = bidx[bs * KK + mrow];
    const short8* arow = reinterpret_cast<const short8*>(featT + ((size_t)(b * Nn + p)) * Cc);

    // xyz chunk (k = 256..258 of layer-1 A), nonzero only in quad 0, j=0..2
    short8 a1x = {0, 0, 0, 0, 0, 0, 0, 0};
    {
        const float cx = new_xyz[bs * 3 + 0];
        const float cy = new_xyz[bs * 3 + 1];
        const float cz = new_xyz[bs * 3 + 2];
        const float px = xyz[((size_t)(b * Nn + p)) * 3 + 0];
        const float py = xyz[((size_t)(b * Nn + p)) * 3 + 1];
        const float pz = xyz[((size_t)(b * Nn + p)) * 3 + 2];
        if (quad == 0) {
            a1x.s0 = (short)f2bf((px - cx) / 0.3f);
            a1x.s1 = (short)f2bf((py - cy) / 0.3f);
            a1x.s2 = (short)f2bf((pz - cz) / 0.3f);
        }
    }

    const short8* wt0 = reinterpret_cast<const short8*>(Wt0);
    const short8* wt1 = reinterpret_cast<const short8*>(Wt1);
    const short8* wt2 = reinterpret_cast<const short8*>(Wt2);
    const short8* yv = reinterpret_cast<const short8*>(ylds);

    f32x4 acc[8] = {};

    // ---- layer 1: K = 288 (9 chunks of 32) ----
    {
        short8 acur = arow[0 * 4 + quad];
        short8 anxt;
        short8 bcur[8], bnxt[8];
#pragma unroll
        for (int nt = 0; nt < 8; nt++)
            bcur[nt] = wt0[(nt * 16 + mrow) * (KP1 / 8) + 0 * 4 + quad];
        for (int kc = 0; kc < 9; kc++) {
            if (kc < 8) {
                if (kc < 7) anxt = arow[(kc + 1) * 4 + quad];
                else anxt = a1x;
#pragma unroll
                for (int nt = 0; nt < 8; nt++)
                    bnxt[nt] = wt0[(nt * 16 + mrow) * (KP1 / 8) + (kc + 1) * 4 + quad];
            }
#pragma unroll
            for (int nt = 0; nt < 8; nt++)
                acc[nt] = __builtin_amdgcn_mfma_f32_16x16x32_bf16(acur, bcur[nt], acc[nt], 0, 0, 0);
            acur = anxt;
#pragma unroll
            for (int nt = 0; nt < 8; nt++) bcur[nt] = bnxt[nt];
        }
    }
    // epilogue 1 -> ylds (bf16, [m][n] with row stride YSTR)
#pragma unroll
    for (int nt = 0; nt < 8; nt++) {
        const int n = nt * 16 + mrow;
        const float sc = scbi[0 * 128 + n];
        const float bi = scbi[1 * 128 + n];
#pragma unroll
        for (int r = 0; r < 4; r++) {
            const float z = fmaxf(acc[nt][r] * sc + bi, 0.0f);
            ylds[(quad * 4 + r) * YSTR + n] = f2bf(z);
        }
    }
    __syncthreads();

    // ---- layer 2: K = 128 (4 chunks) ----
#pragma unroll
    for (int nt = 0; nt < 8; nt++) acc[nt] = (f32x4){0.f, 0.f, 0.f, 0.f};
    {
        short8 acur = yv[mrow * (YSTR / 8) + 0 * 4 + quad];
        short8 anxt;
        short8 bcur[8], bnxt[8];
#pragma unroll
        for (int nt = 0; nt < 8; nt++)
            bcur[nt] = wt1[(nt * 16 + mrow) * 16 + 0 * 4 + quad];
        for (int kc = 0; kc < 4; kc++) {
            if (kc < 3) {
                anxt = yv[mrow * (YSTR / 8) + (kc + 1) * 4 + quad];
#pragma unroll
                for (int nt = 0; nt < 8; nt++)
                    bnxt[nt] = wt1[(nt * 16 + mrow) * 16 + (kc + 1) * 4 + quad];
            }
#pragma unroll
            for (int nt = 0; nt < 8; nt++)
                acc[nt] = __builtin_amdgcn_mfma_f32_16x16x32_bf16(acur, bcur[nt], acc[nt], 0, 0, 0);
            acur = anxt;
#pragma unroll
            for (int nt = 0; nt < 8; nt++) bcur[nt] = bnxt[nt];
        }
    }
    __syncthreads();  // all reads of ylds done before overwrite
#pragma unroll
    for (int nt = 0; nt < 8; nt++) {
        const int n = nt * 16 + mrow;
        const float sc = scbi[2 * 128 + n];
        const float bi = scbi[3 * 128 + n];
#pragma unroll
        for (int r = 0; r < 4; r++) {
            const float z = fmaxf(acc[nt][r] * sc + bi, 0.0f);
            ylds[(quad * 4 + r) * YSTR + n] = f2bf(z);
        }
    }
    __syncthreads();

    // ---- layer 3: K = 128 (4 chunks), then BN+relu+maxpool over m ----
#pragma unroll
    for (int nt = 0; nt < 8; nt++) acc[nt] = (f32x4){0.f, 0.f, 0.f, 0.f};
    {
        short8 acur = yv[mrow * (YSTR / 8) + 0 * 4 + quad];
        short8 anxt;
        short8 bcur[8], bnxt[8];
#pragma unroll
        for (int nt = 0; nt < 8; nt++)
            bcur[nt] = wt2[(nt * 16 + mrow) * 16 + 0 * 4 + quad];
        for (int kc = 0; kc < 4; kc++) {
            if (kc < 3) {
                anxt = yv[mrow * (YSTR / 8) + (kc + 1) * 4 + quad];
#pragma unroll
                for (int nt = 0; nt < 8; nt++)
                    bnxt[nt] = wt2[(nt * 16 + mrow) * 16 + (kc + 1) * 4 + quad];
            }
#pragma unroll
            for (int nt = 0; nt < 8; nt++)
                acc[nt] = __builtin_amdgcn_mfma_f32_16x16x32_bf16(acur, bcur[nt], acc[nt], 0, 0, 0);
            acur = anxt;
#pragma unroll
            for (int nt = 0; nt < 8; nt++) bcur[nt] = bnxt[nt];
        }
    }
#pragma unroll
    for (int nt = 0; nt < 8; nt++) {
        const int n = nt * 16 + mrow;
        const float sc = scbi[4 * 128 + n];
        const float bi = scbi[5 * 128 + n];
        float vmax = 0.0f;  // relu output >= 0
#pragma unroll
        for (int r = 0; r < 4; r++)
            vmax = fmaxf(vmax, acc[nt][r] * sc + bi);
        vmax = fmaxf(vmax, __shfl_xor(vmax, 16));
        vmax = fmaxf(vmax, __shfl_xor(vmax, 32));
        if (quad == 0) pooled[(size_t)bs * H + n] = vmax;
    }
}

// ---------------- FC head (128->128->128->79) + decode ----------------
__global__ __launch_bounds__(128) void head_kernel(
    const float* __restrict__ pooled, const float* __restrict__ new_xyz,
    const float* __restrict__ c1w, const float* __restrict__ c1b,
    const float* __restrict__ g3, const float* __restrict__ be3,
    const float* __restrict__ m3, const float* __restrict__ v3,
    const float* __restrict__ c2w, const float* __restrict__ c2b,
    const float* __restrict__ g4, const float* __restrict__ be4,
    const float* __restrict__ m4, const float* __restrict__ v4,
    const float* __restrict__ c3w, const float* __restrict__ c3b,
    float* __restrict__ out) {
    const int bs = blockIdx.x;
    const int t = threadIdx.x;
    __shared__ __align__(16) float y0[128];
    __shared__ __align__(16) float y1[128];
    __shared__ __align__(16) float y2[128];
    __shared__ float net[OUTC];

    y0[t] = pooled[(size_t)bs * H + t];
    const float sA = g3[t] / sqrtf(v3[t] + 1e-5f);
    const float bA = (c1b[t] - m3[t]) * sA + be3[t];
    const float sB = g4[t] / sqrtf(v4[t] + 1e-5f);
    const float bB = (c2b[t] - m4[t]) * sB + be4[t];
    __syncthreads();

    float acc = 0.0f;
    for (int i4 = 0; i4 < 32; i4++) {
        const int i = i4 * 4;
        const float4 xv = *reinterpret_cast<const float4*>(&y0[i]);
        acc += xv.x * c1w[(i + 0) * H + t] + xv.y * c1w[(i + 1) * H + t] +
               xv.z * c1w[(i + 2) * H + t] + xv.w * c1w[(i + 3) * H + t];
    }
    y1[t] = fmaxf(acc * sA + bA, 0.0f);
    __syncthreads();

    acc = 0.0f;
    for (int i4 = 0; i4 < 32; i4++) {
        const int i = i4 * 4;
        const float4 xv = *reinterpret_cast<const float4*>(&y1[i]);
        acc += xv.x * c2w[(i + 0) * H + t] + xv.y * c2w[(i + 1) * H + t] +
               xv.z * c2w[(i + 2) * H + t] + xv.w * c2w[(i + 3) * H + t];
    }
    y2[t] = fmaxf(acc * sB + bB, 0.0f);
    __syncthreads();

    if (t < OUTC) {
        float a = c3b[t];
        for (int i4 = 0; i4 < 32; i4++) {
            const int i = i4 * 4;
            const float4 xv = *reinterpret_cast<const float4*>(&y2[i]);
            a += xv.x * c3w[(i + 0) * OUTC + t] + xv.y * c3w[(i + 1) * OUTC + t] +
                 xv.z * c3w[(i + 2) * OUTC + t] + xv.w * c3w[(i + 3) * OUTC + t];
        }
        net[t] = a;
    }
    __syncthreads();

    if (t < ODIM) {
        const float* nz = new_xyz + (size_t)bs * 3;
        float val;
        if (t < 3) val = nz[t];
        else if (t < 5) val = net[t - 3];
        else if (t < 8) val = nz[t - 5] + net[2 + (t - 5)];
        else if (t < 20) val = net[5 + (t - 8)];
        else if (t < 32) val = net[17 + (t - 20)];
        else if (t < 44) val = net[17 + (t - 32)] * (float)(3.14159265358979323846 / 12.0);
        else if (t < 54) val = net[29 + (t - 44)];
        else if (t < 84) val = net[39 + (t - 54)];
        else if (t < 114) val = net[39 + (t - 84)] * MEANF[t - 84];
        else val = net[69 + (t - 114)];
        out[(size_t)bs * ODIM + t] = val;
    }
}

extern "C" void kernel_launch(void* const* d_in, const int* in_sizes, int n_in,
                              void* d_out, int out_size, void* d_ws, size_t ws_size,
                              hipStream_t stream) {
    (void)in_sizes; (void)n_in; (void)out_size; (void)ws_size;
    const float* xyz = (const float*)d_in[0];
    const float* features = (const float*)d_in[1];
    const float* w0 = (const float*)d_in[2];
    const float* bb0 = (const float*)d_in[3];
    const float* g0 = (const float*)d_in[4];
    const float* be0 = (const float*)d_in[5];
    const float* m0 = (const float*)d_in[6];
    const float* v0 = (const float*)d_in[7];
    const float* w1 = (const float*)d_in[8];
    const float* bb1 = (const float*)d_in[9];
    const float* g1 = (const float*)d_in[10];
    const float* be1 = (const float*)d_in[11];
    const float* m1 = (const float*)d_in[12];
    const float* v1 = (const float*)d_in[13];
    const float* w2 = (const float*)d_in[14];
    const float* bb2 = (const float*)d_in[15];
    const float* g2 = (const float*)d_in[16];
    const float* be2 = (const float*)d_in[17];
    const float* m2 = (const float*)d_in[18];
    const float* v2 = (const float*)d_in[19];
    const float* c1w = (const float*)d_in[20];
    const float* c1b = (const float*)d_in[21];
    const float* g3 = (const float*)d_in[22];
    const float* be3 = (const float*)d_in[23];
    const float* m3 = (const float*)d_in[24];
    const float* v3 = (const float*)d_in[25];
    const float* c2w = (const float*)d_in[26];
    const float* c2b = (const float*)d_in[27];
    const float* g4 = (const float*)d_in[28];
    const float* be4 = (const float*)d_in[29];
    const float* m4 = (const float*)d_in[30];
    const float* v4 = (const float*)d_in[31];
    const float* c3w = (const float*)d_in[32];
    const float* c3b = (const float*)d_in[33];
    float* out = (float*)d_out;

    // workspace layout (byte offsets, all 16B aligned)
    char* ws = (char*)d_ws;
    int* fps_idx = (int*)(ws + 0);                       // 4096 i32      -> 16384
    float* nxyz = (float*)(ws + 16384);                  // 12288 f32     -> 65536
    int* bidx = (int*)(ws + 65536);                      // 65536 i32     -> 327680
    float* scbi = (float*)(ws + 327680);                 // 768 f32       -> 330752
    unsigned short* Wt0 = (unsigned short*)(ws + 330752);  // 128*288 us  -> 404480
    unsigned short* Wt1 = (unsigned short*)(ws + 404480);  // 128*128 us  -> 437248
    unsigned short* Wt2 = (unsigned short*)(ws + 437248);  // 128*128 us  -> 470016
    float* pooled = (float*)(ws + 470016);               // 4096*128 f32  -> 2567168
    unsigned short* featT = (unsigned short*)(ws + 2567168);  // 32*2048*256 us -> ~36.1MB

    hipLaunchKernelGGL(prep_kernel, dim3(144), dim3(256), 0, stream,
                       w0, bb0, g0, be0, m0, v0,
                       w1, bb1, g1, be1, m1, v1,
                       w2, bb2, g2, be2, m2, v2,
                       Wt0, Wt1, Wt2, scbi);
    hipLaunchKernelGGL(fps_kernel, dim3(Bn), dim3(256), 0, stream, xyz, fps_idx, nxyz);
    hipLaunchKernelGGL(transpose_bf16_kernel, dim3(Nn / 32, Cc / 64, Bn), dim3(256), 0, stream,
                       features, featT);
    hipLaunchKernelGGL(ballq_kernel, dim3(Bn * Sn), dim3(64), 0, stream, xyz, nxyz, bidx);
    hipLaunchKernelGGL(groupmlp_mfma_kernel, dim3(Bn * Sn / 4), dim3(256), 0, stream,
                       xyz, featT, nxyz, bidx, Wt0, Wt1, Wt2, scbi, pooled);
    hipLaunchKernelGGL(head_kernel, dim3(Bn * Sn), dim3(128), 0, stream, pooled, nxyz,
                       c1w, c1b, g3, be3, m3, v3,
                       c2w, c2b, g4, be4, m4, v4,
                       c3w, c3b, out);
}

// Round 4
// 386.189 us; speedup vs baseline: 1.4920x; 1.0739x over previous
//
#include <hip/hip_runtime.h>
#include <hip/hip_bf16.h>
#include <math.h>

#define Bn 32
#define Nn 2048
#define Cc 256
#define Sn 128
#define KK 16
#define H 128
#define OUTC 79
#define ODIM 124
#define KP1 288  // layer-1 K padded: 256 features + 3 xyz + 29 zeros

typedef __attribute__((ext_vector_type(8))) short short8;
typedef __attribute__((ext_vector_type(4))) float f32x4;
typedef unsigned long long ull;

__device__ __constant__ float MEANF[30] = {
    0.76584f, 1.398258f, 0.472728f,
    2.114256f, 1.6203f, 0.927272f,
    0.404671f, 1.071108f, 1.688889f,
    0.591958f, 0.552978f, 0.827272f,
    0.69519f, 1.346299f, 0.736364f,
    0.528526f, 1.002642f, 1.172878f,
    0.500618f, 0.632163f, 0.683424f,
    0.923508f, 1.867419f, 0.845495f,
    0.791118f, 1.279516f, 0.718182f,
    0.699104f, 0.454178f, 0.75625f};

__device__ __forceinline__ unsigned short f2bf(float f) {
    __hip_bfloat16 h = __float2bfloat16(f);
    return *reinterpret_cast<unsigned short*>(&h);
}

__device__ __forceinline__ ull umax64(ull a, ull b) { return a > b ? a : b; }

// ---------------- fused FPS (blocks 0..31) + feature transpose (rest) ----------------
// FPS: one block per batch, 256 threads, coords in registers (8 pts/lane),
// u64 packed-key argmax: (fbits<<32)|(2047-p) -> max = (max dist, min index).
// Transpose: (B,C,N) fp32 -> (B,N,C) bf16, 64x32 tiles.
struct SmemFPS {
    float xs[Nn * 3];          // 24576 B
    ull red[2][4];             // parity-double-buffered per-wave winners
};
struct SmemT {
    float tile[64][33];        // 33792 B
};
__global__ __launch_bounds__(256) void fps_transpose_kernel(const float* __restrict__ xyz,
                                                            const float* __restrict__ features,
                                                            float* __restrict__ new_xyz,
                                                            unsigned short* __restrict__ fT) {
    __shared__ __align__(16) char smem_raw[sizeof(SmemT) > sizeof(SmemFPS) ? sizeof(SmemT)
                                                                           : sizeof(SmemFPS)];
    const int bid = blockIdx.x;
    if (bid >= Bn) {
        // ---- transpose role ----
        SmemT* sm = (SmemT*)smem_raw;
        const int tb = bid - Bn;
        const int b = tb >> 8;            // 256 tiles per batch
        const int rem = tb & 255;
        const int n0 = (rem & 63) * 32;   // 64 n-tiles
        const int c0 = (rem >> 6) * 64;   // 4 c-tiles
        const int tx = threadIdx.x & 31;
        const int ty = threadIdx.x >> 5;  // 0..7
        for (int i = ty; i < 64; i += 8)
            sm->tile[i][tx] = features[((size_t)b * Cc + (c0 + i)) * Nn + n0 + tx];
        __syncthreads();
        for (int n = ty; n < 32; n += 8) {
            const float lo = sm->tile[tx * 2 + 0][n];
            const float hi = sm->tile[tx * 2 + 1][n];
            const unsigned int v = (unsigned int)f2bf(lo) | ((unsigned int)f2bf(hi) << 16);
            *reinterpret_cast<unsigned int*>(&fT[((size_t)b * Nn + (n0 + n)) * Cc + c0 + tx * 2]) = v;
        }
        return;
    }
    // ---- FPS role ----
    {
#pragma clang fp contract(off)
        SmemFPS* sm = (SmemFPS*)smem_raw;
        float* xs = sm->xs;
        const int b = bid;
        const int t = threadIdx.x;
        const int lane = t & 63;
        const int wv = t >> 6;

        {
            float4* xs4 = (float4*)xs;
            const float4* src = (const float4*)(xyz + (size_t)b * Nn * 3);
            for (int i = t; i < Nn * 3 / 4; i += 256) xs4[i] = src[i];
        }
        __syncthreads();

        const int base = wv * 512 + lane;
        float px[8], py[8], pz[8], mind[8];
        int klo[8];
#pragma unroll
        for (int j = 0; j < 8; j++) {
            const int p = base + j * 64;
            px[j] = xs[p * 3 + 0];
            py[j] = xs[p * 3 + 1];
            pz[j] = xs[p * 3 + 2];
            mind[j] = 1e10f;
            klo[j] = 2047 - p;
        }
        float lx = xs[0], ly = xs[1], lz = xs[2];

        for (int it = 0; it < Sn; ++it) {
            if (t == 0) {
                new_xyz[((size_t)b * Sn + it) * 3 + 0] = lx;
                new_xyz[((size_t)b * Sn + it) * 3 + 1] = ly;
                new_xyz[((size_t)b * Sn + it) * 3 + 2] = lz;
            }
            ull kk[8];
#pragma unroll
            for (int j = 0; j < 8; j++) {
                const float dx = px[j] - lx;
                const float dy = py[j] - ly;
                const float dz = pz[j] - lz;
                const float dx2 = dx * dx;
                const float dy2 = dy * dy;
                const float dz2 = dz * dz;
                const float s01 = dx2 + dy2;
                const float d = s01 + dz2;
                const float m = fminf(mind[j], d);
                mind[j] = m;
                kk[j] = ((ull)__float_as_uint(m) << 32) | (unsigned int)klo[j];
            }
            ull k0 = umax64(kk[0], kk[1]);
            ull k1 = umax64(kk[2], kk[3]);
            ull k2 = umax64(kk[4], kk[5]);
            ull k3 = umax64(kk[6], kk[7]);
            k0 = umax64(k0, k1);
            k2 = umax64(k2, k3);
            ull bk = umax64(k0, k2);
#pragma unroll
            for (int off = 1; off < 64; off <<= 1) {
                const ull o = __shfl_xor(bk, off);
                bk = umax64(bk, o);
            }
            if (lane == 0) sm->red[it & 1][wv] = bk;
            __syncthreads();
            ull r0 = sm->red[it & 1][0];
            ull r1 = sm->red[it & 1][1];
            ull r2 = sm->red[it & 1][2];
            ull r3 = sm->red[it & 1][3];
            bk = umax64(umax64(r0, r1), umax64(r2, r3));
            const int last = 2047 - (int)(bk & 0xffffffffull);
            lx = xs[last * 3 + 0];
            ly = xs[last * 3 + 1];
            lz = xs[last * 3 + 2];
        }
    }
}

// ---------------- prep: fold BN, transpose+pad weights to bf16 Wt[n][k] ----------------
__global__ __launch_bounds__(256) void prep_kernel(
    const float* __restrict__ w0, const float* __restrict__ bb0,
    const float* __restrict__ g0, const float* __restrict__ be0,
    const float* __restrict__ m0, const float* __restrict__ v0,
    const float* __restrict__ w1, const float* __restrict__ bb1,
    const float* __restrict__ g1, const float* __restrict__ be1,
    const float* __restrict__ m1, const float* __restrict__ v1,
    const float* __restrict__ w2, const float* __restrict__ bb2,
    const float* __restrict__ g2, const float* __restrict__ be2,
    const float* __restrict__ m2, const float* __restrict__ v2,
    unsigned short* __restrict__ Wt0, unsigned short* __restrict__ Wt1,
    unsigned short* __restrict__ Wt2, float* __restrict__ scbi) {
    const int idx = blockIdx.x * 256 + threadIdx.x;
    if (idx < 128 * KP1) {
        const int n = idx / KP1;
        const int k = idx - n * KP1;
        float v = 0.0f;
        if (k < 256) v = w0[(3 + k) * H + n];
        else if (k < 259) v = w0[(k - 256) * H + n];
        Wt0[idx] = f2bf(v);
    }
    if (idx < 128 * 128) {
        const int n = idx >> 7;
        const int k = idx & 127;
        Wt1[idx] = f2bf(w1[k * H + n]);
        Wt2[idx] = f2bf(w2[k * H + n]);
    }
    if (idx < 128) {
        const float sc1 = g0[idx] / sqrtf(v0[idx] + 1e-5f);
        scbi[0 * 128 + idx] = sc1;
        scbi[1 * 128 + idx] = (bb0[idx] - m0[idx]) * sc1 + be0[idx];
        const float sc2 = g1[idx] / sqrtf(v1[idx] + 1e-5f);
        scbi[2 * 128 + idx] = sc2;
        scbi[3 * 128 + idx] = (bb1[idx] - m1[idx]) * sc2 + be1[idx];
        const float sc3 = g2[idx] / sqrtf(v2[idx] + 1e-5f);
        scbi[4 * 128 + idx] = sc3;
        scbi[5 * 128 + idx] = (bb2[idx] - m2[idx]) * sc3 + be2[idx];
    }
}

// ---------------- grouped MLP via MFMA, ball-query fused: one wave per (b,s) ----------------
#define YSTR 136  // LDS row stride in bf16 units (272B, 16B-aligned)
__global__ __launch_bounds__(256) void groupmlp_mfma_kernel(
    const float* __restrict__ xyz, const unsigned short* __restrict__ featT,
    const float* __restrict__ new_xyz,
    const unsigned short* __restrict__ Wt0, const unsigned short* __restrict__ Wt1,
    const unsigned short* __restrict__ Wt2, const float* __restrict__ scbi,
    float* __restrict__ pooled) {
    const int wv = threadIdx.x >> 6;
    const int lane = threadIdx.x & 63;
    const int bs = blockIdx.x * 4 + wv;
    const int b = bs >> 7;
    const int mrow = lane & 15;
    const int quad = lane >> 4;

    __shared__ unsigned short ylds_all[4][16 * YSTR];
    __shared__ int sbuf[4][16];
    unsigned short* ylds = &ylds_all[wv][0];

    // ---- fused ball query (first-16 ascending indices within radius) ----
    const float cx = new_xyz[bs * 3 + 0];
    const float cy = new_xyz[bs * 3 + 1];
    const float cz = new_xyz[bs * 3 + 2];
    int basec = 0;
    {
#pragma clang fp contract(off)
        for (int c0 = 0; c0 < Nn && basec < KK; c0 += 64) {
            const int p = c0 + lane;
            const float dx = xyz[((size_t)b * Nn + p) * 3 + 0] - cx;
            const float dy = xyz[((size_t)b * Nn + p) * 3 + 1] - cy;
            const float dz = xyz[((size_t)b * Nn + p) * 3 + 2] - cz;
            const float dx2 = dx * dx;
            const float dy2 = dy * dy;
            const float dz2 = dz * dz;
            const float s01 = dx2 + dy2;
            const float d2 = s01 + dz2;
            const bool q = d2 < 0.09f;
            const ull mask = __ballot(q);
            const int prefix = __popcll(mask & ((1ull << lane) - 1ull));
            const int slot = basec + prefix;
            if (q && slot < KK) sbuf[wv][slot] = p;
            basec += __popcll(mask);
        }
    }
    const int cnt = basec < KK ? basec : KK;
    const int p = sbuf[wv][mrow < cnt ? mrow : 0];

    const short8* arow = reinterpret_cast<const short8*>(featT + ((size_t)(b * Nn + p)) * Cc);

    // xyz chunk (k=256..258 of layer-1 A), nonzero only in quad 0
    short8 a1x = {0, 0, 0, 0, 0, 0, 0, 0};
    {
        const float fx = xyz[((size_t)(b * Nn + p)) * 3 + 0];
        const float fy = xyz[((size_t)(b * Nn + p)) * 3 + 1];
        const float fz = xyz[((size_t)(b * Nn + p)) * 3 + 2];
        if (quad == 0) {
            a1x.s0 = (short)f2bf((fx - cx) / 0.3f);
            a1x.s1 = (short)f2bf((fy - cy) / 0.3f);
            a1x.s2 = (short)f2bf((fz - cz) / 0.3f);
        }
    }

    const short8* wt0 = reinterpret_cast<const short8*>(Wt0);
    const short8* wt1 = reinterpret_cast<const short8*>(Wt1);
    const short8* wt2 = reinterpret_cast<const short8*>(Wt2);
    const short8* yv = reinterpret_cast<const short8*>(ylds);

    f32x4 acc[8] = {};

    // ---- layer 1: K = 288 (9 chunks of 32) ----
    {
        short8 acur = arow[quad];
        short8 anxt;
        short8 bcur[8], bnxt[8];
#pragma unroll
        for (int nt = 0; nt < 8; nt++)
            bcur[nt] = wt0[(nt * 16 + mrow) * (KP1 / 8) + quad];
        for (int kc = 0; kc < 9; kc++) {
            if (kc < 8) {
                if (kc < 7) anxt = arow[(kc + 1) * 4 + quad];
                else anxt = a1x;
#pragma unroll
                for (int nt = 0; nt < 8; nt++)
                    bnxt[nt] = wt0[(nt * 16 + mrow) * (KP1 / 8) + (kc + 1) * 4 + quad];
            }
#pragma unroll
            for (int nt = 0; nt < 8; nt++)
                acc[nt] = __builtin_amdgcn_mfma_f32_16x16x32_bf16(acur, bcur[nt], acc[nt], 0, 0, 0);
            acur = anxt;
#pragma unroll
            for (int nt = 0; nt < 8; nt++) bcur[nt] = bnxt[nt];
        }
    }
#pragma unroll
    for (int nt = 0; nt < 8; nt++) {
        const int n = nt * 16 + mrow;
        const float sc = scbi[0 * 128 + n];
        const float bi = scbi[1 * 128 + n];
#pragma unroll
        for (int r = 0; r < 4; r++) {
            const float z = fmaxf(acc[nt][r] * sc + bi, 0.0f);
            ylds[(quad * 4 + r) * YSTR + n] = f2bf(z);
        }
    }
    __syncthreads();

    // ---- layer 2: K = 128 ----
#pragma unroll
    for (int nt = 0; nt < 8; nt++) acc[nt] = (f32x4){0.f, 0.f, 0.f, 0.f};
    {
        short8 acur = yv[mrow * (YSTR / 8) + quad];
        short8 anxt;
        short8 bcur[8], bnxt[8];
#pragma unroll
        for (int nt = 0; nt < 8; nt++)
            bcur[nt] = wt1[(nt * 16 + mrow) * 16 + quad];
        for (int kc = 0; kc < 4; kc++) {
            if (kc < 3) {
                anxt = yv[mrow * (YSTR / 8) + (kc + 1) * 4 + quad];
#pragma unroll
                for (int nt = 0; nt < 8; nt++)
                    bnxt[nt] = wt1[(nt * 16 + mrow) * 16 + (kc + 1) * 4 + quad];
            }
#pragma unroll
            for (int nt = 0; nt < 8; nt++)
                acc[nt] = __builtin_amdgcn_mfma_f32_16x16x32_bf16(acur, bcur[nt], acc[nt], 0, 0, 0);
            acur = anxt;
#pragma unroll
            for (int nt = 0; nt < 8; nt++) bcur[nt] = bnxt[nt];
        }
    }
    __syncthreads();
#pragma unroll
    for (int nt = 0; nt < 8; nt++) {
        const int n = nt * 16 + mrow;
        const float sc = scbi[2 * 128 + n];
        const float bi = scbi[3 * 128 + n];
#pragma unroll
        for (int r = 0; r < 4; r++) {
            const float z = fmaxf(acc[nt][r] * sc + bi, 0.0f);
            ylds[(quad * 4 + r) * YSTR + n] = f2bf(z);
        }
    }
    __syncthreads();

    // ---- layer 3: K = 128, then BN+relu+maxpool over m ----
#pragma unroll
    for (int nt = 0; nt < 8; nt++) acc[nt] = (f32x4){0.f, 0.f, 0.f, 0.f};
    {
        short8 acur = yv[mrow * (YSTR / 8) + quad];
        short8 anxt;
        short8 bcur[8], bnxt[8];
#pragma unroll
        for (int nt = 0; nt < 8; nt++)
            bcur[nt] = wt2[(nt * 16 + mrow) * 16 + quad];
        for (int kc = 0; kc < 4; kc++) {
            if (kc < 3) {
                anxt = yv[mrow * (YSTR / 8) + (kc + 1) * 4 + quad];
#pragma unroll
                for (int nt = 0; nt < 8; nt++)
                    bnxt[nt] = wt2[(nt * 16 + mrow) * 16 + (kc + 1) * 4 + quad];
            }
#pragma unroll
            for (int nt = 0; nt < 8; nt++)
                acc[nt] = __builtin_amdgcn_mfma_f32_16x16x32_bf16(acur, bcur[nt], acc[nt], 0, 0, 0);
            acur = anxt;
#pragma unroll
            for (int nt = 0; nt < 8; nt++) bcur[nt] = bnxt[nt];
        }
    }
#pragma unroll
    for (int nt = 0; nt < 8; nt++) {
        const int n = nt * 16 + mrow;
        const float sc = scbi[4 * 128 + n];
        const float bi = scbi[5 * 128 + n];
        float vmax = 0.0f;  // relu output >= 0
#pragma unroll
        for (int r = 0; r < 4; r++)
            vmax = fmaxf(vmax, acc[nt][r] * sc + bi);
        vmax = fmaxf(vmax, __shfl_xor(vmax, 16));
        vmax = fmaxf(vmax, __shfl_xor(vmax, 32));
        if (quad == 0) pooled[(size_t)bs * H + n] = vmax;
    }
}

// ---------------- FC head: 8 proposals per block, weights staged in LDS ----------------
__global__ __launch_bounds__(128) void head_kernel(
    const float* __restrict__ pooled, const float* __restrict__ new_xyz,
    const float* __restrict__ c1w, const float* __restrict__ c1b,
    const float* __restrict__ g3, const float* __restrict__ be3,
    const float* __restrict__ m3, const float* __restrict__ v3,
    const float* __restrict__ c2w, const float* __restrict__ c2b,
    const float* __restrict__ g4, const float* __restrict__ be4,
    const float* __restrict__ m4, const float* __restrict__ v4,
    const float* __restrict__ c3w, const float* __restrict__ c3b,
    float* __restrict__ out) {
    const int t = threadIdx.x;
    const int bs0 = blockIdx.x * 8;
    __shared__ __align__(16) float wbuf[16384];   // 64 KB weight stage
    __shared__ __align__(16) float xb[8][128];
    __shared__ __align__(16) float yb[8][128];

    const float sA = g3[t] / sqrtf(v3[t] + 1e-5f);
    const float bA = (c1b[t] - m3[t]) * sA + be3[t];
    const float sB = g4[t] / sqrtf(v4[t] + 1e-5f);
    const float bB = (c2b[t] - m4[t]) * sB + be4[t];
    const float c3bias = (t < OUTC) ? c3b[t] : 0.0f;

#pragma unroll
    for (int u = 0; u < 8; u++) xb[u][t] = pooled[(size_t)(bs0 + u) * H + t];
    for (int i = t; i < 4096; i += 128)
        ((float4*)wbuf)[i] = ((const float4*)c1w)[i];
    __syncthreads();

#pragma unroll
    for (int u = 0; u < 8; u++) {
        float acc = 0.0f;
        for (int i4 = 0; i4 < 32; i4++) {
            const int i = i4 * 4;
            const float4 xv = *reinterpret_cast<const float4*>(&xb[u][i]);
            acc += xv.x * wbuf[(i + 0) * H + t] + xv.y * wbuf[(i + 1) * H + t] +
                   xv.z * wbuf[(i + 2) * H + t] + xv.w * wbuf[(i + 3) * H + t];
        }
        yb[u][t] = fmaxf(acc * sA + bA, 0.0f);
    }
    __syncthreads();
    for (int i = t; i < 4096; i += 128)
        ((float4*)wbuf)[i] = ((const float4*)c2w)[i];
    __syncthreads();

#pragma unroll
    for (int u = 0; u < 8; u++) {
        float acc = 0.0f;
        for (int i4 = 0; i4 < 32; i4++) {
            const int i = i4 * 4;
            const float4 xv = *reinterpret_cast<const float4*>(&yb[u][i]);
            acc += xv.x * wbuf[(i + 0) * H + t] + xv.y * wbuf[(i + 1) * H + t] +
                   xv.z * wbuf[(i + 2) * H + t] + xv.w * wbuf[(i + 3) * H + t];
        }
        xb[u][t] = fmaxf(acc * sB + bB, 0.0f);
    }
    __syncthreads();
    for (int i = t; i < 2528; i += 128)  // 128*79/4
        ((float4*)wbuf)[i] = ((const float4*)c3w)[i];
    __syncthreads();

#pragma unroll
    for (int u = 0; u < 8; u++) {
        if (t < OUTC) {
            float acc = c3bias;
            for (int i4 = 0; i4 < 32; i4++) {
                const int i = i4 * 4;
                const float4 xv = *reinterpret_cast<const float4*>(&xb[u][i]);
                acc += xv.x * wbuf[(i + 0) * OUTC + t] + xv.y * wbuf[(i + 1) * OUTC + t] +
                       xv.z * wbuf[(i + 2) * OUTC + t] + xv.w * wbuf[(i + 3) * OUTC + t];
            }
            yb[u][t] = acc;
        }
    }
    __syncthreads();

#pragma unroll
    for (int u = 0; u < 8; u++) {
        if (t < ODIM) {
            const float* nz = new_xyz + (size_t)(bs0 + u) * 3;
            const float* net = &yb[u][0];
            float val;
            if (t < 3) val = nz[t];
            else if (t < 5) val = net[t - 3];
            else if (t < 8) val = nz[t - 5] + net[2 + (t - 5)];
            else if (t < 20) val = net[5 + (t - 8)];
            else if (t < 32) val = net[17 + (t - 20)];
            else if (t < 44) val = net[17 + (t - 32)] * (float)(3.14159265358979323846 / 12.0);
            else if (t < 54) val = net[29 + (t - 44)];
            else if (t < 84) val = net[39 + (t - 54)];
            else if (t < 114) val = net[39 + (t - 84)] * MEANF[t - 84];
            else val = net[69 + (t - 114)];
            out[(size_t)(bs0 + u) * ODIM + t] = val;
        }
    }
}

extern "C" void kernel_launch(void* const* d_in, const int* in_sizes, int n_in,
                              void* d_out, int out_size, void* d_ws, size_t ws_size,
                              hipStream_t stream) {
    (void)in_sizes; (void)n_in; (void)out_size; (void)ws_size;
    const float* xyz = (const float*)d_in[0];
    const float* features = (const float*)d_in[1];
    const float* w0 = (const float*)d_in[2];
    const float* bb0 = (const float*)d_in[3];
    const float* g0 = (const float*)d_in[4];
    const float* be0 = (const float*)d_in[5];
    const float* m0 = (const float*)d_in[6];
    const float* v0 = (const float*)d_in[7];
    const float* w1 = (const float*)d_in[8];
    const float* bb1 = (const float*)d_in[9];
    const float* g1 = (const float*)d_in[10];
    const float* be1 = (const float*)d_in[11];
    const float* m1 = (const float*)d_in[12];
    const float* v1 = (const float*)d_in[13];
    const float* w2 = (const float*)d_in[14];
    const float* bb2 = (const float*)d_in[15];
    const float* g2 = (const float*)d_in[16];
    const float* be2 = (const float*)d_in[17];
    const float* m2 = (const float*)d_in[18];
    const float* v2 = (const float*)d_in[19];
    const float* c1w = (const float*)d_in[20];
    const float* c1b = (const float*)d_in[21];
    const float* g3 = (const float*)d_in[22];
    const float* be3 = (const float*)d_in[23];
    const float* m3 = (const float*)d_in[24];
    const float* v3 = (const float*)d_in[25];
    const float* c2w = (const float*)d_in[26];
    const float* c2b = (const float*)d_in[27];
    const float* g4 = (const float*)d_in[28];
    const float* be4 = (const float*)d_in[29];
    const float* m4 = (const float*)d_in[30];
    const float* v4 = (const float*)d_in[31];
    const float* c3w = (const float*)d_in[32];
    const float* c3b = (const float*)d_in[33];
    float* out = (float*)d_out;

    // workspace layout (byte offsets, 16B aligned)
    char* ws = (char*)d_ws;
    float* nxyz = (float*)(ws + 0);                           // 12288 f32   -> 49152
    float* scbi = (float*)(ws + 49152);                       // 768 f32     -> 52224
    unsigned short* Wt0 = (unsigned short*)(ws + 52224);      // 128*288 bf  -> 125952
    unsigned short* Wt1 = (unsigned short*)(ws + 125952);     // 128*128 bf  -> 158720
    unsigned short* Wt2 = (unsigned short*)(ws + 158720);     // 128*128 bf  -> 191488
    float* pooled = (float*)(ws + 191488);                    // 4096*128 f32-> 2288640
    unsigned short* featT = (unsigned short*)(ws + 2288640);  // 32*2048*256 bf16

    hipLaunchKernelGGL(prep_kernel, dim3(144), dim3(256), 0, stream,
                       w0, bb0, g0, be0, m0, v0,
                       w1, bb1, g1, be1, m1, v1,
                       w2, bb2, g2, be2, m2, v2,
                       Wt0, Wt1, Wt2, scbi);
    hipLaunchKernelGGL(fps_transpose_kernel, dim3(Bn + Bn * 256), dim3(256), 0, stream,
                       xyz, features, nxyz, featT);
    hipLaunchKernelGGL(groupmlp_mfma_kernel, dim3(Bn * Sn / 4), dim3(256), 0, stream,
                       xyz, featT, nxyz, Wt0, Wt1, Wt2, scbi, pooled);
    hipLaunchKernelGGL(head_kernel, dim3(Bn * Sn / 8), dim3(128), 0, stream, pooled, nxyz,
                       c1w, c1b, g3, be3, m3, v3,
                       c2w, c2b, g4, be4, m4, v4,
                       c3w, c3b, out);
}

// Round 5
// 320.499 us; speedup vs baseline: 1.7978x; 1.2050x over previous
//
#include <hip/hip_runtime.h>
#include <hip/hip_bf16.h>
#include <math.h>

#define Bn 32
#define Nn 2048
#define Cc 256
#define Sn 128
#define KK 16
#define H 128
#define OUTC 79
#define ODIM 124
#define KP1 288  // layer-1 K padded: 256 features + 3 xyz + 29 zeros

typedef __attribute__((ext_vector_type(8))) short short8;
typedef __attribute__((ext_vector_type(4))) float f32x4;
typedef unsigned long long ull;

__device__ __constant__ float MEANF[30] = {
    0.76584f, 1.398258f, 0.472728f,
    2.114256f, 1.6203f, 0.927272f,
    0.404671f, 1.071108f, 1.688889f,
    0.591958f, 0.552978f, 0.827272f,
    0.69519f, 1.346299f, 0.736364f,
    0.528526f, 1.002642f, 1.172878f,
    0.500618f, 0.632163f, 0.683424f,
    0.923508f, 1.867419f, 0.845495f,
    0.791118f, 1.279516f, 0.718182f,
    0.699104f, 0.454178f, 0.75625f};

__device__ __forceinline__ unsigned short f2bf(float f) {
    __hip_bfloat16 h = __float2bfloat16(f);
    return *reinterpret_cast<unsigned short*>(&h);
}

__device__ __forceinline__ ull umax64(ull a, ull b) { return a > b ? a : b; }

// ---------------- fused FPS (blocks 0..31) + feature transpose (rest) ----------------
struct SmemFPS {
    float xs[Nn * 3];
    ull red[2][4];
};
struct SmemT {
    float tile[64][33];
};
__global__ __launch_bounds__(256) void fps_transpose_kernel(const float* __restrict__ xyz,
                                                            const float* __restrict__ features,
                                                            float* __restrict__ new_xyz,
                                                            unsigned short* __restrict__ fT) {
    __shared__ __align__(16) char smem_raw[sizeof(SmemT) > sizeof(SmemFPS) ? sizeof(SmemT)
                                                                           : sizeof(SmemFPS)];
    const int bid = blockIdx.x;
    if (bid >= Bn) {
        // ---- transpose role ----
        SmemT* sm = (SmemT*)smem_raw;
        const int tb = bid - Bn;
        const int b = tb >> 8;
        const int rem = tb & 255;
        const int n0 = (rem & 63) * 32;
        const int c0 = (rem >> 6) * 64;
        const int tx = threadIdx.x & 31;
        const int ty = threadIdx.x >> 5;
        for (int i = ty; i < 64; i += 8)
            sm->tile[i][tx] = features[((size_t)b * Cc + (c0 + i)) * Nn + n0 + tx];
        __syncthreads();
        for (int n = ty; n < 32; n += 8) {
            const float lo = sm->tile[tx * 2 + 0][n];
            const float hi = sm->tile[tx * 2 + 1][n];
            const unsigned int v = (unsigned int)f2bf(lo) | ((unsigned int)f2bf(hi) << 16);
            *reinterpret_cast<unsigned int*>(&fT[((size_t)b * Nn + (n0 + n)) * Cc + c0 + tx * 2]) = v;
        }
        return;
    }
    // ---- FPS role ----
    {
#pragma clang fp contract(off)
        SmemFPS* sm = (SmemFPS*)smem_raw;
        float* xs = sm->xs;
        const int b = bid;
        const int t = threadIdx.x;
        const int lane = t & 63;
        const int wv = t >> 6;

        {
            float4* xs4 = (float4*)xs;
            const float4* src = (const float4*)(xyz + (size_t)b * Nn * 3);
            for (int i = t; i < Nn * 3 / 4; i += 256) xs4[i] = src[i];
        }
        __syncthreads();

        const int base = wv * 512 + lane;
        float px[8], py[8], pz[8], mind[8];
        int klo[8];
#pragma unroll
        for (int j = 0; j < 8; j++) {
            const int p = base + j * 64;
            px[j] = xs[p * 3 + 0];
            py[j] = xs[p * 3 + 1];
            pz[j] = xs[p * 3 + 2];
            mind[j] = 1e10f;
            klo[j] = 2047 - p;
        }
        float lx = xs[0], ly = xs[1], lz = xs[2];

        for (int it = 0; it < Sn; ++it) {
            if (t == 0) {
                new_xyz[((size_t)b * Sn + it) * 3 + 0] = lx;
                new_xyz[((size_t)b * Sn + it) * 3 + 1] = ly;
                new_xyz[((size_t)b * Sn + it) * 3 + 2] = lz;
            }
            ull kk[8];
#pragma unroll
            for (int j = 0; j < 8; j++) {
                const float dx = px[j] - lx;
                const float dy = py[j] - ly;
                const float dz = pz[j] - lz;
                const float dx2 = dx * dx;
                const float dy2 = dy * dy;
                const float dz2 = dz * dz;
                const float s01 = dx2 + dy2;
                const float d = s01 + dz2;
                const float m = fminf(mind[j], d);
                mind[j] = m;
                kk[j] = ((ull)__float_as_uint(m) << 32) | (unsigned int)klo[j];
            }
            ull k0 = umax64(kk[0], kk[1]);
            ull k1 = umax64(kk[2], kk[3]);
            ull k2 = umax64(kk[4], kk[5]);
            ull k3 = umax64(kk[6], kk[7]);
            k0 = umax64(k0, k1);
            k2 = umax64(k2, k3);
            ull bk = umax64(k0, k2);
#pragma unroll
            for (int off = 1; off < 64; off <<= 1) {
                const ull o = __shfl_xor(bk, off);
                bk = umax64(bk, o);
            }
            if (lane == 0) sm->red[it & 1][wv] = bk;
            __syncthreads();
            ull r0 = sm->red[it & 1][0];
            ull r1 = sm->red[it & 1][1];
            ull r2 = sm->red[it & 1][2];
            ull r3 = sm->red[it & 1][3];
            bk = umax64(umax64(r0, r1), umax64(r2, r3));
            const int last = 2047 - (int)(bk & 0xffffffffull);
            lx = xs[last * 3 + 0];
            ly = xs[last * 3 + 1];
            lz = xs[last * 3 + 2];
        }
    }
}

// ---------------- prep: fold BN, transpose all weights to bf16 Wt[n][k] ----------------
__global__ __launch_bounds__(256) void prep_kernel(
    const float* __restrict__ w0, const float* __restrict__ bb0,
    const float* __restrict__ g0, const float* __restrict__ be0,
    const float* __restrict__ m0, const float* __restrict__ v0,
    const float* __restrict__ w1, const float* __restrict__ bb1,
    const float* __restrict__ g1, const float* __restrict__ be1,
    const float* __restrict__ m1, const float* __restrict__ v1,
    const float* __restrict__ w2, const float* __restrict__ bb2,
    const float* __restrict__ g2, const float* __restrict__ be2,
    const float* __restrict__ m2, const float* __restrict__ v2,
    const float* __restrict__ c1w, const float* __restrict__ c1b,
    const float* __restrict__ g3, const float* __restrict__ be3,
    const float* __restrict__ m3, const float* __restrict__ v3,
    const float* __restrict__ c2w, const float* __restrict__ c2b,
    const float* __restrict__ g4, const float* __restrict__ be4,
    const float* __restrict__ m4, const float* __restrict__ v4,
    const float* __restrict__ c3w, const float* __restrict__ c3b,
    unsigned short* __restrict__ Wt0, unsigned short* __restrict__ Wt1,
    unsigned short* __restrict__ Wt2, unsigned short* __restrict__ Wc1t,
    unsigned short* __restrict__ Wc2t, unsigned short* __restrict__ Wc3t,
    float* __restrict__ scbi, float* __restrict__ scbiH) {
    const int idx = blockIdx.x * 256 + threadIdx.x;
    if (idx < 128 * KP1) {
        const int n = idx / KP1;
        const int k = idx - n * KP1;
        float v = 0.0f;
        if (k < 256) v = w0[(3 + k) * H + n];
        else if (k < 259) v = w0[(k - 256) * H + n];
        Wt0[idx] = f2bf(v);
    }
    if (idx < 128 * 128) {
        const int n = idx >> 7;
        const int k = idx & 127;
        Wt1[idx] = f2bf(w1[k * H + n]);
        Wt2[idx] = f2bf(w2[k * H + n]);
        Wc1t[idx] = f2bf(c1w[k * H + n]);
        Wc2t[idx] = f2bf(c2w[k * H + n]);
    }
    if (idx < 80 * 128) {
        const int n = idx >> 7;
        const int k = idx & 127;
        Wc3t[idx] = (n < OUTC) ? f2bf(c3w[k * OUTC + n]) : (unsigned short)0;
    }
    if (idx < 128) {
        const float sc1 = g0[idx] / sqrtf(v0[idx] + 1e-5f);
        scbi[0 * 128 + idx] = sc1;
        scbi[1 * 128 + idx] = (bb0[idx] - m0[idx]) * sc1 + be0[idx];
        const float sc2 = g1[idx] / sqrtf(v1[idx] + 1e-5f);
        scbi[2 * 128 + idx] = sc2;
        scbi[3 * 128 + idx] = (bb1[idx] - m1[idx]) * sc2 + be1[idx];
        const float sc3 = g2[idx] / sqrtf(v2[idx] + 1e-5f);
        scbi[4 * 128 + idx] = sc3;
        scbi[5 * 128 + idx] = (bb2[idx] - m2[idx]) * sc3 + be2[idx];
        const float sA = g3[idx] / sqrtf(v3[idx] + 1e-5f);
        scbiH[0 * 128 + idx] = sA;
        scbiH[1 * 128 + idx] = (c1b[idx] - m3[idx]) * sA + be3[idx];
        const float sB = g4[idx] / sqrtf(v4[idx] + 1e-5f);
        scbiH[2 * 128 + idx] = sB;
        scbiH[3 * 128 + idx] = (c2b[idx] - m4[idx]) * sB + be4[idx];
    }
    if (idx < 80) scbiH[512 + idx] = (idx < OUTC) ? c3b[idx] : 0.0f;
}

// ---------------- grouped MLP via MFMA, ball-query fused: one wave per (b,s) ----------------
// ylds is wave-private: no __syncthreads needed (in-wave LDS RAW ordered by waitcnt).
#define YSTR 136  // LDS row stride in bf16 units (272B, 16B-aligned)
__global__ __launch_bounds__(256) void groupmlp_mfma_kernel(
    const float* __restrict__ xyz, const unsigned short* __restrict__ featT,
    const float* __restrict__ new_xyz,
    const unsigned short* __restrict__ Wt0, const unsigned short* __restrict__ Wt1,
    const unsigned short* __restrict__ Wt2, const float* __restrict__ scbi,
    unsigned short* __restrict__ pooledb) {
    const int wv = threadIdx.x >> 6;
    const int lane = threadIdx.x & 63;
    const int bs = blockIdx.x * 4 + wv;
    const int b = bs >> 7;
    const int mrow = lane & 15;
    const int quad = lane >> 4;

    __shared__ unsigned short ylds_all[4][16 * YSTR];
    __shared__ int sbuf[4][16];
    unsigned short* ylds = &ylds_all[wv][0];

    // ---- fused ball query (first-16 ascending indices within radius) ----
    const float cx = new_xyz[bs * 3 + 0];
    const float cy = new_xyz[bs * 3 + 1];
    const float cz = new_xyz[bs * 3 + 2];
    int basec = 0;
    {
#pragma clang fp contract(off)
        for (int c0 = 0; c0 < Nn && basec < KK; c0 += 64) {
            const int p = c0 + lane;
            const float dx = xyz[((size_t)b * Nn + p) * 3 + 0] - cx;
            const float dy = xyz[((size_t)b * Nn + p) * 3 + 1] - cy;
            const float dz = xyz[((size_t)b * Nn + p) * 3 + 2] - cz;
            const float dx2 = dx * dx;
            const float dy2 = dy * dy;
            const float dz2 = dz * dz;
            const float s01 = dx2 + dy2;
            const float d2 = s01 + dz2;
            const bool q = d2 < 0.09f;
            const ull mask = __ballot(q);
            const int prefix = __popcll(mask & ((1ull << lane) - 1ull));
            const int slot = basec + prefix;
            if (q && slot < KK) sbuf[wv][slot] = p;
            basec += __popcll(mask);
        }
    }
    const int cnt = basec < KK ? basec : KK;
    const int p = sbuf[wv][mrow < cnt ? mrow : 0];

    const short8* arow = reinterpret_cast<const short8*>(featT + ((size_t)(b * Nn + p)) * Cc);

    short8 a1x = {0, 0, 0, 0, 0, 0, 0, 0};
    {
        const float fx = xyz[((size_t)(b * Nn + p)) * 3 + 0];
        const float fy = xyz[((size_t)(b * Nn + p)) * 3 + 1];
        const float fz = xyz[((size_t)(b * Nn + p)) * 3 + 2];
        if (quad == 0) {
            a1x.s0 = (short)f2bf((fx - cx) / 0.3f);
            a1x.s1 = (short)f2bf((fy - cy) / 0.3f);
            a1x.s2 = (short)f2bf((fz - cz) / 0.3f);
        }
    }

    const short8* wt0 = reinterpret_cast<const short8*>(Wt0);
    const short8* wt1 = reinterpret_cast<const short8*>(Wt1);
    const short8* wt2 = reinterpret_cast<const short8*>(Wt2);
    const short8* yv = reinterpret_cast<const short8*>(ylds);

    f32x4 acc[8] = {};

    // ---- layer 1: K = 288 ----
    {
        short8 acur = arow[quad];
        short8 anxt;
        short8 bcur[8], bnxt[8];
#pragma unroll
        for (int nt = 0; nt < 8; nt++)
            bcur[nt] = wt0[(nt * 16 + mrow) * (KP1 / 8) + quad];
        for (int kc = 0; kc < 9; kc++) {
            if (kc < 8) {
                if (kc < 7) anxt = arow[(kc + 1) * 4 + quad];
                else anxt = a1x;
#pragma unroll
                for (int nt = 0; nt < 8; nt++)
                    bnxt[nt] = wt0[(nt * 16 + mrow) * (KP1 / 8) + (kc + 1) * 4 + quad];
            }
#pragma unroll
            for (int nt = 0; nt < 8; nt++)
                acc[nt] = __builtin_amdgcn_mfma_f32_16x16x32_bf16(acur, bcur[nt], acc[nt], 0, 0, 0);
            acur = anxt;
#pragma unroll
            for (int nt = 0; nt < 8; nt++) bcur[nt] = bnxt[nt];
        }
    }
#pragma unroll
    for (int nt = 0; nt < 8; nt++) {
        const int n = nt * 16 + mrow;
        const float sc = scbi[0 * 128 + n];
        const float bi = scbi[1 * 128 + n];
#pragma unroll
        for (int r = 0; r < 4; r++) {
            const float z = fmaxf(acc[nt][r] * sc + bi, 0.0f);
            ylds[(quad * 4 + r) * YSTR + n] = f2bf(z);
        }
    }

    // ---- layer 2: K = 128 ----
#pragma unroll
    for (int nt = 0; nt < 8; nt++) acc[nt] = (f32x4){0.f, 0.f, 0.f, 0.f};
    {
        short8 acur = yv[mrow * (YSTR / 8) + quad];
        short8 anxt;
        short8 bcur[8], bnxt[8];
#pragma unroll
        for (int nt = 0; nt < 8; nt++)
            bcur[nt] = wt1[(nt * 16 + mrow) * 16 + quad];
        for (int kc = 0; kc < 4; kc++) {
            if (kc < 3) {
                anxt = yv[mrow * (YSTR / 8) + (kc + 1) * 4 + quad];
#pragma unroll
                for (int nt = 0; nt < 8; nt++)
                    bnxt[nt] = wt1[(nt * 16 + mrow) * 16 + (kc + 1) * 4 + quad];
            }
#pragma unroll
            for (int nt = 0; nt < 8; nt++)
                acc[nt] = __builtin_amdgcn_mfma_f32_16x16x32_bf16(acur, bcur[nt], acc[nt], 0, 0, 0);
            acur = anxt;
#pragma unroll
            for (int nt = 0; nt < 8; nt++) bcur[nt] = bnxt[nt];
        }
    }
#pragma unroll
    for (int nt = 0; nt < 8; nt++) {
        const int n = nt * 16 + mrow;
        const float sc = scbi[2 * 128 + n];
        const float bi = scbi[3 * 128 + n];
#pragma unroll
        for (int r = 0; r < 4; r++) {
            const float z = fmaxf(acc[nt][r] * sc + bi, 0.0f);
            ylds[(quad * 4 + r) * YSTR + n] = f2bf(z);
        }
    }

    // ---- layer 3: K = 128, then BN+relu+maxpool over m ----
#pragma unroll
    for (int nt = 0; nt < 8; nt++) acc[nt] = (f32x4){0.f, 0.f, 0.f, 0.f};
    {
        short8 acur = yv[mrow * (YSTR / 8) + quad];
        short8 anxt;
        short8 bcur[8], bnxt[8];
#pragma unroll
        for (int nt = 0; nt < 8; nt++)
            bcur[nt] = wt2[(nt * 16 + mrow) * 16 + quad];
        for (int kc = 0; kc < 4; kc++) {
            if (kc < 3) {
                anxt = yv[mrow * (YSTR / 8) + (kc + 1) * 4 + quad];
#pragma unroll
                for (int nt = 0; nt < 8; nt++)
                    bnxt[nt] = wt2[(nt * 16 + mrow) * 16 + (kc + 1) * 4 + quad];
            }
#pragma unroll
            for (int nt = 0; nt < 8; nt++)
                acc[nt] = __builtin_amdgcn_mfma_f32_16x16x32_bf16(acur, bcur[nt], acc[nt], 0, 0, 0);
            acur = anxt;
#pragma unroll
            for (int nt = 0; nt < 8; nt++) bcur[nt] = bnxt[nt];
        }
    }
#pragma unroll
    for (int nt = 0; nt < 8; nt++) {
        const int n = nt * 16 + mrow;
        const float sc = scbi[4 * 128 + n];
        const float bi = scbi[5 * 128 + n];
        float vmax = 0.0f;  // relu output >= 0
#pragma unroll
        for (int r = 0; r < 4; r++)
            vmax = fmaxf(vmax, acc[nt][r] * sc + bi);
        vmax = fmaxf(vmax, __shfl_xor(vmax, 16));
        vmax = fmaxf(vmax, __shfl_xor(vmax, 32));
        if (quad == 0) pooledb[(size_t)bs * H + n] = f2bf(vmax);
    }
}

// ---------------- FC head via MFMA: one wave per 16 proposals + fused decode ----------------
__global__ __launch_bounds__(64) void head_mfma_kernel(
    const unsigned short* __restrict__ pooledb, const float* __restrict__ new_xyz,
    const unsigned short* __restrict__ Wc1t, const unsigned short* __restrict__ Wc2t,
    const unsigned short* __restrict__ Wc3t, const float* __restrict__ scbiH,
    float* __restrict__ out) {
    const int lane = threadIdx.x;
    const int row0 = blockIdx.x * 16;
    const int mrow = lane & 15;
    const int quad = lane >> 4;

    __shared__ unsigned short ylds[16 * YSTR];
    __shared__ float flds[16 * 84];

    const short8* ar = reinterpret_cast<const short8*>(pooledb + (size_t)(row0 + mrow) * H);
    const short8* w1h = reinterpret_cast<const short8*>(Wc1t);
    const short8* w2h = reinterpret_cast<const short8*>(Wc2t);
    const short8* w3h = reinterpret_cast<const short8*>(Wc3t);
    const short8* yv = reinterpret_cast<const short8*>(ylds);

    // ---- layer A: y1 = relu(x@c1 * sA + bA), K=128, N=128 ----
    f32x4 acc[8] = {};
#pragma unroll
    for (int kc = 0; kc < 4; kc++) {
        const short8 a = ar[kc * 4 + quad];
#pragma unroll
        for (int nt = 0; nt < 8; nt++) {
            const short8 bf = w1h[(nt * 16 + mrow) * 16 + kc * 4 + quad];
            acc[nt] = __builtin_amdgcn_mfma_f32_16x16x32_bf16(a, bf, acc[nt], 0, 0, 0);
        }
    }
#pragma unroll
    for (int nt = 0; nt < 8; nt++) {
        const int n = nt * 16 + mrow;
        const float sc = scbiH[0 * 128 + n];
        const float bi = scbiH[1 * 128 + n];
#pragma unroll
        for (int r = 0; r < 4; r++) {
            const float z = fmaxf(acc[nt][r] * sc + bi, 0.0f);
            ylds[(quad * 4 + r) * YSTR + n] = f2bf(z);
        }
    }

    // ---- layer B: y2 = relu(y1@c2 * sB + bB) ----
#pragma unroll
    for (int nt = 0; nt < 8; nt++) acc[nt] = (f32x4){0.f, 0.f, 0.f, 0.f};
#pragma unroll
    for (int kc = 0; kc < 4; kc++) {
        const short8 a = yv[mrow * (YSTR / 8) + kc * 4 + quad];
#pragma unroll
        for (int nt = 0; nt < 8; nt++) {
            const short8 bf = w2h[(nt * 16 + mrow) * 16 + kc * 4 + quad];
            acc[nt] = __builtin_amdgcn_mfma_f32_16x16x32_bf16(a, bf, acc[nt], 0, 0, 0);
        }
    }
#pragma unroll
    for (int nt = 0; nt < 8; nt++) {
        const int n = nt * 16 + mrow;
        const float sc = scbiH[2 * 128 + n];
        const float bi = scbiH[3 * 128 + n];
#pragma unroll
        for (int r = 0; r < 4; r++) {
            const float z = fmaxf(acc[nt][r] * sc + bi, 0.0f);
            ylds[(quad * 4 + r) * YSTR + n] = f2bf(z);
        }
    }

    // ---- layer C: net = y2@c3 + c3b, N=80 (col 79 = pad) ----
    f32x4 acc3[5] = {};
#pragma unroll
    for (int kc = 0; kc < 4; kc++) {
        const short8 a = yv[mrow * (YSTR / 8) + kc * 4 + quad];
#pragma unroll
        for (int nt = 0; nt < 5; nt++) {
            const short8 bf = w3h[(nt * 16 + mrow) * 16 + kc * 4 + quad];
            acc3[nt] = __builtin_amdgcn_mfma_f32_16x16x32_bf16(a, bf, acc3[nt], 0, 0, 0);
        }
    }
#pragma unroll
    for (int nt = 0; nt < 5; nt++) {
        const int n = nt * 16 + mrow;
        const float bi = scbiH[512 + n];
#pragma unroll
        for (int r = 0; r < 4; r++)
            flds[(quad * 4 + r) * 84 + n] = acc3[nt][r] + bi;
    }

    // ---- fused decode: 16 rows x 124 cols, coalesced stores ----
    for (int m = 0; m < 16; m++) {
        const int row = row0 + m;
        const float* net = &flds[m * 84];
        const float* nz = new_xyz + (size_t)row * 3;
#pragma unroll
        for (int jj = 0; jj < 2; jj++) {
            const int j = lane + jj * 64;
            if (j < ODIM) {
                float val;
                if (j < 3) val = nz[j];
                else if (j < 5) val = net[j - 3];
                else if (j < 8) val = nz[j - 5] + net[2 + (j - 5)];
                else if (j < 20) val = net[5 + (j - 8)];
                else if (j < 32) val = net[17 + (j - 20)];
                else if (j < 44) val = net[17 + (j - 32)] * (float)(3.14159265358979323846 / 12.0);
                else if (j < 54) val = net[29 + (j - 44)];
                else if (j < 84) val = net[39 + (j - 54)];
                else if (j < 114) val = net[39 + (j - 84)] * MEANF[j - 84];
                else val = net[69 + (j - 114)];
                out[(size_t)row * ODIM + j] = val;
            }
        }
    }
}

extern "C" void kernel_launch(void* const* d_in, const int* in_sizes, int n_in,
                              void* d_out, int out_size, void* d_ws, size_t ws_size,
                              hipStream_t stream) {
    (void)in_sizes; (void)n_in; (void)out_size; (void)ws_size;
    const float* xyz = (const float*)d_in[0];
    const float* features = (const float*)d_in[1];
    const float* w0 = (const float*)d_in[2];
    const float* bb0 = (const float*)d_in[3];
    const float* g0 = (const float*)d_in[4];
    const float* be0 = (const float*)d_in[5];
    const float* m0 = (const float*)d_in[6];
    const float* v0 = (const float*)d_in[7];
    const float* w1 = (const float*)d_in[8];
    const float* bb1 = (const float*)d_in[9];
    const float* g1 = (const float*)d_in[10];
    const float* be1 = (const float*)d_in[11];
    const float* m1 = (const float*)d_in[12];
    const float* v1 = (const float*)d_in[13];
    const float* w2 = (const float*)d_in[14];
    const float* bb2 = (const float*)d_in[15];
    const float* g2 = (const float*)d_in[16];
    const float* be2 = (const float*)d_in[17];
    const float* m2 = (const float*)d_in[18];
    const float* v2 = (const float*)d_in[19];
    const float* c1w = (const float*)d_in[20];
    const float* c1b = (const float*)d_in[21];
    const float* g3 = (const float*)d_in[22];
    const float* be3 = (const float*)d_in[23];
    const float* m3 = (const float*)d_in[24];
    const float* v3 = (const float*)d_in[25];
    const float* c2w = (const float*)d_in[26];
    const float* c2b = (const float*)d_in[27];
    const float* g4 = (const float*)d_in[28];
    const float* be4 = (const float*)d_in[29];
    const float* m4 = (const float*)d_in[30];
    const float* v4 = (const float*)d_in[31];
    const float* c3w = (const float*)d_in[32];
    const float* c3b = (const float*)d_in[33];
    float* out = (float*)d_out;

    // workspace layout (byte offsets, 16B aligned)
    char* ws = (char*)d_ws;
    float* nxyz = (float*)(ws + 0);                            // 12288 f32  -> 49152
    float* scbi = (float*)(ws + 49152);                        // 768 f32    -> 52224
    unsigned short* Wt0 = (unsigned short*)(ws + 52224);       // 36864 bf   -> 125952
    unsigned short* Wt1 = (unsigned short*)(ws + 125952);      // 16384 bf   -> 158720
    unsigned short* Wt2 = (unsigned short*)(ws + 158720);      // 16384 bf   -> 191488
    unsigned short* Wc1t = (unsigned short*)(ws + 191488);     // 16384 bf   -> 224256
    unsigned short* Wc2t = (unsigned short*)(ws + 224256);     // 16384 bf   -> 257024
    unsigned short* Wc3t = (unsigned short*)(ws + 257024);     // 10240 bf   -> 277504
    float* scbiH = (float*)(ws + 277504);                      // 592 f32    -> 279872
    unsigned short* pooledb = (unsigned short*)(ws + 279872);  // 524288 bf  -> 1328448
    unsigned short* featT = (unsigned short*)(ws + 1328448);   // 32*2048*256 bf16

    hipLaunchKernelGGL(prep_kernel, dim3(144), dim3(256), 0, stream,
                       w0, bb0, g0, be0, m0, v0,
                       w1, bb1, g1, be1, m1, v1,
                       w2, bb2, g2, be2, m2, v2,
                       c1w, c1b, g3, be3, m3, v3,
                       c2w, c2b, g4, be4, m4, v4,
                       c3w, c3b,
                       Wt0, Wt1, Wt2, Wc1t, Wc2t, Wc3t, scbi, scbiH);
    hipLaunchKernelGGL(fps_transpose_kernel, dim3(Bn + Bn * 256), dim3(256), 0, stream,
                       xyz, features, nxyz, featT);
    hipLaunchKernelGGL(groupmlp_mfma_kernel, dim3(Bn * Sn / 4), dim3(256), 0, stream,
                       xyz, featT, nxyz, Wt0, Wt1, Wt2, scbi, pooledb);
    hipLaunchKernelGGL(head_mfma_kernel, dim3(Bn * Sn / 16), dim3(64), 0, stream,
                       pooledb, nxyz, Wc1t, Wc2t, Wc3t, scbiH, out);
}

// Round 6
// 302.695 us; speedup vs baseline: 1.9035x; 1.0588x over previous
//
#include <hip/hip_runtime.h>
#include <hip/hip_bf16.h>
#include <math.h>

#define Bn 32
#define Nn 2048
#define Cc 256
#define Sn 128
#define KK 16
#define H 128
#define OUTC 79
#define ODIM 124
#define KP1 288  // layer-1 K padded: 256 features + 3 xyz + 29 zeros

typedef __attribute__((ext_vector_type(8))) short short8;
typedef __attribute__((ext_vector_type(4))) float f32x4;
typedef unsigned long long ull;

__device__ __constant__ float MEANF[30] = {
    0.76584f, 1.398258f, 0.472728f,
    2.114256f, 1.6203f, 0.927272f,
    0.404671f, 1.071108f, 1.688889f,
    0.591958f, 0.552978f, 0.827272f,
    0.69519f, 1.346299f, 0.736364f,
    0.528526f, 1.002642f, 1.172878f,
    0.500618f, 0.632163f, 0.683424f,
    0.923508f, 1.867419f, 0.845495f,
    0.791118f, 1.279516f, 0.718182f,
    0.699104f, 0.454178f, 0.75625f};

__device__ __forceinline__ unsigned short f2bf(float f) {
    __hip_bfloat16 h = __float2bfloat16(f);
    return *reinterpret_cast<unsigned short*>(&h);
}

__device__ __forceinline__ ull umax64(ull a, ull b) { return a > b ? a : b; }

// ---------------- fused FPS (blocks 0..31) + feature transpose (rest) ----------------
struct SmemFPS {
    float xs[Nn * 3];
    ull red[2][4];
};
struct SmemT {
    float tile[64][33];
};
__global__ __launch_bounds__(256) void fps_transpose_kernel(const float* __restrict__ xyz,
                                                            const float* __restrict__ features,
                                                            float* __restrict__ new_xyz,
                                                            unsigned short* __restrict__ fT) {
    __shared__ __align__(16) char smem_raw[sizeof(SmemT) > sizeof(SmemFPS) ? sizeof(SmemT)
                                                                           : sizeof(SmemFPS)];
    const int bid = blockIdx.x;
    if (bid >= Bn) {
        // ---- transpose role ----
        SmemT* sm = (SmemT*)smem_raw;
        const int tb = bid - Bn;
        const int b = tb >> 8;
        const int rem = tb & 255;
        const int n0 = (rem & 63) * 32;
        const int c0 = (rem >> 6) * 64;
        const int tx = threadIdx.x & 31;
        const int ty = threadIdx.x >> 5;
        for (int i = ty; i < 64; i += 8)
            sm->tile[i][tx] = features[((size_t)b * Cc + (c0 + i)) * Nn + n0 + tx];
        __syncthreads();
        for (int n = ty; n < 32; n += 8) {
            const float lo = sm->tile[tx * 2 + 0][n];
            const float hi = sm->tile[tx * 2 + 1][n];
            const unsigned int v = (unsigned int)f2bf(lo) | ((unsigned int)f2bf(hi) << 16);
            *reinterpret_cast<unsigned int*>(&fT[((size_t)b * Nn + (n0 + n)) * Cc + c0 + tx * 2]) = v;
        }
        return;
    }
    // ---- FPS role ----
    {
#pragma clang fp contract(off)
        SmemFPS* sm = (SmemFPS*)smem_raw;
        float* xs = sm->xs;
        const int b = bid;
        const int t = threadIdx.x;
        const int lane = t & 63;
        const int wv = t >> 6;

        {
            float4* xs4 = (float4*)xs;
            const float4* src = (const float4*)(xyz + (size_t)b * Nn * 3);
            for (int i = t; i < Nn * 3 / 4; i += 256) xs4[i] = src[i];
        }
        __syncthreads();

        const int base = wv * 512 + lane;
        float px[8], py[8], pz[8], mind[8];
        int klo[8];
#pragma unroll
        for (int j = 0; j < 8; j++) {
            const int p = base + j * 64;
            px[j] = xs[p * 3 + 0];
            py[j] = xs[p * 3 + 1];
            pz[j] = xs[p * 3 + 2];
            mind[j] = 1e10f;
            klo[j] = 2047 - p;
        }
        float lx = xs[0], ly = xs[1], lz = xs[2];

        for (int it = 0; it < Sn; ++it) {
            if (t == 0) {
                new_xyz[((size_t)b * Sn + it) * 3 + 0] = lx;
                new_xyz[((size_t)b * Sn + it) * 3 + 1] = ly;
                new_xyz[((size_t)b * Sn + it) * 3 + 2] = lz;
            }
            ull kk[8];
#pragma unroll
            for (int j = 0; j < 8; j++) {
                const float dx = px[j] - lx;
                const float dy = py[j] - ly;
                const float dz = pz[j] - lz;
                const float dx2 = dx * dx;
                const float dy2 = dy * dy;
                const float dz2 = dz * dz;
                const float s01 = dx2 + dy2;
                const float d = s01 + dz2;
                const float m = fminf(mind[j], d);
                mind[j] = m;
                kk[j] = ((ull)__float_as_uint(m) << 32) | (unsigned int)klo[j];
            }
            ull k0 = umax64(kk[0], kk[1]);
            ull k1 = umax64(kk[2], kk[3]);
            ull k2 = umax64(kk[4], kk[5]);
            ull k3 = umax64(kk[6], kk[7]);
            k0 = umax64(k0, k1);
            k2 = umax64(k2, k3);
            ull bk = umax64(k0, k2);
#pragma unroll
            for (int off = 1; off < 64; off <<= 1) {
                const ull o = __shfl_xor(bk, off);
                bk = umax64(bk, o);
            }
            if (lane == 0) sm->red[it & 1][wv] = bk;
            __syncthreads();
            ull r0 = sm->red[it & 1][0];
            ull r1 = sm->red[it & 1][1];
            ull r2 = sm->red[it & 1][2];
            ull r3 = sm->red[it & 1][3];
            bk = umax64(umax64(r0, r1), umax64(r2, r3));
            const int last = 2047 - (int)(bk & 0xffffffffull);
            lx = xs[last * 3 + 0];
            ly = xs[last * 3 + 1];
            lz = xs[last * 3 + 2];
        }
    }
}

// ---------------- prep: fold BN, build FRAGMENT-MAJOR bf16 weights ----------------
// Wf[kc][nt][lane] (short8): value j = W[n = nt*16 + (lane&15)][k = kc*32 + (lane>>4)*8 + j]
// -> inner-loop load (kc*NT+nt)*64+lane is perfectly coalesced (1KB burst).
__device__ __forceinline__ float w0val(const float* __restrict__ w0, int n, int k) {
    if (k < 256) return w0[(3 + k) * H + n];
    if (k < 259) return w0[(k - 256) * H + n];
    return 0.0f;
}

__global__ __launch_bounds__(256) void prep_kernel(
    const float* __restrict__ w0, const float* __restrict__ bb0,
    const float* __restrict__ g0, const float* __restrict__ be0,
    const float* __restrict__ m0, const float* __restrict__ v0,
    const float* __restrict__ w1, const float* __restrict__ bb1,
    const float* __restrict__ g1, const float* __restrict__ be1,
    const float* __restrict__ m1, const float* __restrict__ v1,
    const float* __restrict__ w2, const float* __restrict__ bb2,
    const float* __restrict__ g2, const float* __restrict__ be2,
    const float* __restrict__ m2, const float* __restrict__ v2,
    const float* __restrict__ c1w, const float* __restrict__ c1b,
    const float* __restrict__ g3, const float* __restrict__ be3,
    const float* __restrict__ m3, const float* __restrict__ v3,
    const float* __restrict__ c2w, const float* __restrict__ c2b,
    const float* __restrict__ g4, const float* __restrict__ be4,
    const float* __restrict__ m4, const float* __restrict__ v4,
    const float* __restrict__ c3w, const float* __restrict__ c3b,
    unsigned short* __restrict__ Wf0, unsigned short* __restrict__ Wf1,
    unsigned short* __restrict__ Wf2, unsigned short* __restrict__ Wfc1,
    unsigned short* __restrict__ Wfc2, unsigned short* __restrict__ Wfc3,
    float* __restrict__ scbi, float* __restrict__ scbiH) {
    const int idx = blockIdx.x * 256 + threadIdx.x;

    if (idx < 4608) {  // layer-1: 9 kc x 8 nt x 64 lanes
        const int kc = idx / 512;
        const int rem = idx & 511;
        const int nt = rem >> 6;
        const int lane = rem & 63;
        const int n = nt * 16 + (lane & 15);
        const int kb = kc * 32 + (lane >> 4) * 8;
        union { unsigned short u[8]; uint4 q; } P;
#pragma unroll
        for (int j = 0; j < 8; j++) P.u[j] = f2bf(w0val(w0, n, kb + j));
        ((uint4*)Wf0)[idx] = P.q;
    }
    if (idx < 2048) {  // 128x128 layers: 4 kc x 8 nt x 64 lanes
        const int kc = idx >> 9;
        const int rem = idx & 511;
        const int nt = rem >> 6;
        const int lane = rem & 63;
        const int n = nt * 16 + (lane & 15);
        const int kb = kc * 32 + (lane >> 4) * 8;
        union { unsigned short u[8]; uint4 q; } P1, P2, P3, P4;
#pragma unroll
        for (int j = 0; j < 8; j++) {
            const int k = kb + j;
            P1.u[j] = f2bf(w1[k * H + n]);
            P2.u[j] = f2bf(w2[k * H + n]);
            P3.u[j] = f2bf(c1w[k * H + n]);
            P4.u[j] = f2bf(c2w[k * H + n]);
        }
        ((uint4*)Wf1)[idx] = P1.q;
        ((uint4*)Wf2)[idx] = P2.q;
        ((uint4*)Wfc1)[idx] = P3.q;
        ((uint4*)Wfc2)[idx] = P4.q;
    }
    if (idx < 1280) {  // c3: 4 kc x 5 nt x 64 lanes (N padded to 80)
        const int kc = idx / 320;
        const int rem = idx % 320;
        const int nt = rem / 64;
        const int lane = rem % 64;
        const int n = nt * 16 + (lane & 15);
        const int kb = kc * 32 + (lane >> 4) * 8;
        union { unsigned short u[8]; uint4 q; } P;
#pragma unroll
        for (int j = 0; j < 8; j++)
            P.u[j] = (n < OUTC) ? f2bf(c3w[(kb + j) * OUTC + n]) : (unsigned short)0;
        ((uint4*)Wfc3)[idx] = P.q;
    }
    if (idx < 128) {
        const float sc1 = g0[idx] / sqrtf(v0[idx] + 1e-5f);
        scbi[0 * 128 + idx] = sc1;
        scbi[1 * 128 + idx] = (bb0[idx] - m0[idx]) * sc1 + be0[idx];
        const float sc2 = g1[idx] / sqrtf(v1[idx] + 1e-5f);
        scbi[2 * 128 + idx] = sc2;
        scbi[3 * 128 + idx] = (bb1[idx] - m1[idx]) * sc2 + be1[idx];
        const float sc3 = g2[idx] / sqrtf(v2[idx] + 1e-5f);
        scbi[4 * 128 + idx] = sc3;
        scbi[5 * 128 + idx] = (bb2[idx] - m2[idx]) * sc3 + be2[idx];
        const float sA = g3[idx] / sqrtf(v3[idx] + 1e-5f);
        scbiH[0 * 128 + idx] = sA;
        scbiH[1 * 128 + idx] = (c1b[idx] - m3[idx]) * sA + be3[idx];
        const float sB = g4[idx] / sqrtf(v4[idx] + 1e-5f);
        scbiH[2 * 128 + idx] = sB;
        scbiH[3 * 128 + idx] = (c2b[idx] - m4[idx]) * sB + be4[idx];
    }
    if (idx < 80) scbiH[512 + idx] = (idx < OUTC) ? c3b[idx] : 0.0f;
}

// ---------------- grouped MLP via MFMA, ball-query fused: one wave per (b,s) ----------------
// ylds is wave-private: no __syncthreads needed (in-wave LDS RAW ordered by waitcnt).
#define YSTR 136  // LDS row stride in bf16 units (272B, 16B-aligned)
__global__ __launch_bounds__(256) void groupmlp_mfma_kernel(
    const float* __restrict__ xyz, const unsigned short* __restrict__ featT,
    const float* __restrict__ new_xyz,
    const unsigned short* __restrict__ Wf0, const unsigned short* __restrict__ Wf1,
    const unsigned short* __restrict__ Wf2, const float* __restrict__ scbi,
    unsigned short* __restrict__ pooledb) {
    const int wv = threadIdx.x >> 6;
    const int lane = threadIdx.x & 63;
    const int bs = blockIdx.x * 4 + wv;
    const int b = bs >> 7;
    const int mrow = lane & 15;
    const int quad = lane >> 4;

    __shared__ unsigned short ylds_all[4][16 * YSTR];
    __shared__ int sbuf[4][16];
    unsigned short* ylds = &ylds_all[wv][0];

    // ---- fused ball query (first-16 ascending indices within radius) ----
    const float cx = new_xyz[bs * 3 + 0];
    const float cy = new_xyz[bs * 3 + 1];
    const float cz = new_xyz[bs * 3 + 2];
    int basec = 0;
    {
#pragma clang fp contract(off)
        for (int c0 = 0; c0 < Nn && basec < KK; c0 += 64) {
            const int p = c0 + lane;
            const float dx = xyz[((size_t)b * Nn + p) * 3 + 0] - cx;
            const float dy = xyz[((size_t)b * Nn + p) * 3 + 1] - cy;
            const float dz = xyz[((size_t)b * Nn + p) * 3 + 2] - cz;
            const float dx2 = dx * dx;
            const float dy2 = dy * dy;
            const float dz2 = dz * dz;
            const float s01 = dx2 + dy2;
            const float d2 = s01 + dz2;
            const bool q = d2 < 0.09f;
            const ull mask = __ballot(q);
            const int prefix = __popcll(mask & ((1ull << lane) - 1ull));
            const int slot = basec + prefix;
            if (q && slot < KK) sbuf[wv][slot] = p;
            basec += __popcll(mask);
        }
    }
    const int cnt = basec < KK ? basec : KK;
    const int p = sbuf[wv][mrow < cnt ? mrow : 0];

    const short8* arow = reinterpret_cast<const short8*>(featT + ((size_t)(b * Nn + p)) * Cc);

    short8 a1x = {0, 0, 0, 0, 0, 0, 0, 0};
    {
        const float fx = xyz[((size_t)(b * Nn + p)) * 3 + 0];
        const float fy = xyz[((size_t)(b * Nn + p)) * 3 + 1];
        const float fz = xyz[((size_t)(b * Nn + p)) * 3 + 2];
        if (quad == 0) {
            a1x.s0 = (short)f2bf((fx - cx) / 0.3f);
            a1x.s1 = (short)f2bf((fy - cy) / 0.3f);
            a1x.s2 = (short)f2bf((fz - cz) / 0.3f);
        }
    }

    const short8* wf0 = reinterpret_cast<const short8*>(Wf0);
    const short8* wf1 = reinterpret_cast<const short8*>(Wf1);
    const short8* wf2 = reinterpret_cast<const short8*>(Wf2);
    const short8* yv = reinterpret_cast<const short8*>(ylds);

    f32x4 acc[8] = {};

    // ---- layer 1: K = 288 (9 chunks of 32) ----
    {
        short8 acur = arow[quad];
        short8 anxt;
        short8 bcur[8], bnxt[8];
#pragma unroll
        for (int nt = 0; nt < 8; nt++)
            bcur[nt] = wf0[nt * 64 + lane];
        for (int kc = 0; kc < 9; kc++) {
            if (kc < 8) {
                if (kc < 7) anxt = arow[(kc + 1) * 4 + quad];
                else anxt = a1x;
#pragma unroll
                for (int nt = 0; nt < 8; nt++)
                    bnxt[nt] = wf0[((kc + 1) * 8 + nt) * 64 + lane];
            }
#pragma unroll
            for (int nt = 0; nt < 8; nt++)
                acc[nt] = __builtin_amdgcn_mfma_f32_16x16x32_bf16(acur, bcur[nt], acc[nt], 0, 0, 0);
            acur = anxt;
#pragma unroll
            for (int nt = 0; nt < 8; nt++) bcur[nt] = bnxt[nt];
        }
    }
#pragma unroll
    for (int nt = 0; nt < 8; nt++) {
        const int n = nt * 16 + mrow;
        const float sc = scbi[0 * 128 + n];
        const float bi = scbi[1 * 128 + n];
#pragma unroll
        for (int r = 0; r < 4; r++) {
            const float z = fmaxf(acc[nt][r] * sc + bi, 0.0f);
            ylds[(quad * 4 + r) * YSTR + n] = f2bf(z);
        }
    }

    // ---- layer 2: K = 128 (4 chunks) ----
#pragma unroll
    for (int nt = 0; nt < 8; nt++) acc[nt] = (f32x4){0.f, 0.f, 0.f, 0.f};
    {
        short8 acur = yv[mrow * (YSTR / 8) + quad];
        short8 anxt;
        short8 bcur[8], bnxt[8];
#pragma unroll
        for (int nt = 0; nt < 8; nt++)
            bcur[nt] = wf1[nt * 64 + lane];
        for (int kc = 0; kc < 4; kc++) {
            if (kc < 3) {
                anxt = yv[mrow * (YSTR / 8) + (kc + 1) * 4 + quad];
#pragma unroll
                for (int nt = 0; nt < 8; nt++)
                    bnxt[nt] = wf1[((kc + 1) * 8 + nt) * 64 + lane];
            }
#pragma unroll
            for (int nt = 0; nt < 8; nt++)
                acc[nt] = __builtin_amdgcn_mfma_f32_16x16x32_bf16(acur, bcur[nt], acc[nt], 0, 0, 0);
            acur = anxt;
#pragma unroll
            for (int nt = 0; nt < 8; nt++) bcur[nt] = bnxt[nt];
        }
    }
#pragma unroll
    for (int nt = 0; nt < 8; nt++) {
        const int n = nt * 16 + mrow;
        const float sc = scbi[2 * 128 + n];
        const float bi = scbi[3 * 128 + n];
#pragma unroll
        for (int r = 0; r < 4; r++) {
            const float z = fmaxf(acc[nt][r] * sc + bi, 0.0f);
            ylds[(quad * 4 + r) * YSTR + n] = f2bf(z);
        }
    }

    // ---- layer 3: K = 128, then BN+relu+maxpool over m ----
#pragma unroll
    for (int nt = 0; nt < 8; nt++) acc[nt] = (f32x4){0.f, 0.f, 0.f, 0.f};
    {
        short8 acur = yv[mrow * (YSTR / 8) + quad];
        short8 anxt;
        short8 bcur[8], bnxt[8];
#pragma unroll
        for (int nt = 0; nt < 8; nt++)
            bcur[nt] = wf2[nt * 64 + lane];
        for (int kc = 0; kc < 4; kc++) {
            if (kc < 3) {
                anxt = yv[mrow * (YSTR / 8) + (kc + 1) * 4 + quad];
#pragma unroll
                for (int nt = 0; nt < 8; nt++)
                    bnxt[nt] = wf2[((kc + 1) * 8 + nt) * 64 + lane];
            }
#pragma unroll
            for (int nt = 0; nt < 8; nt++)
                acc[nt] = __builtin_amdgcn_mfma_f32_16x16x32_bf16(acur, bcur[nt], acc[nt], 0, 0, 0);
            acur = anxt;
#pragma unroll
            for (int nt = 0; nt < 8; nt++) bcur[nt] = bnxt[nt];
        }
    }
#pragma unroll
    for (int nt = 0; nt < 8; nt++) {
        const int n = nt * 16 + mrow;
        const float sc = scbi[4 * 128 + n];
        const float bi = scbi[5 * 128 + n];
        float vmax = 0.0f;  // relu output >= 0
#pragma unroll
        for (int r = 0; r < 4; r++)
            vmax = fmaxf(vmax, acc[nt][r] * sc + bi);
        vmax = fmaxf(vmax, __shfl_xor(vmax, 16));
        vmax = fmaxf(vmax, __shfl_xor(vmax, 32));
        if (quad == 0) pooledb[(size_t)bs * H + n] = f2bf(vmax);
    }
}

// ---------------- FC head via MFMA: one wave per 16 proposals + fused decode ----------------
__global__ __launch_bounds__(64) void head_mfma_kernel(
    const unsigned short* __restrict__ pooledb, const float* __restrict__ new_xyz,
    const unsigned short* __restrict__ Wfc1, const unsigned short* __restrict__ Wfc2,
    const unsigned short* __restrict__ Wfc3, const float* __restrict__ scbiH,
    float* __restrict__ out) {
    const int lane = threadIdx.x;
    const int row0 = blockIdx.x * 16;
    const int mrow = lane & 15;
    const int quad = lane >> 4;

    __shared__ unsigned short ylds[16 * YSTR];
    __shared__ float flds[16 * 84];

    const short8* ar = reinterpret_cast<const short8*>(pooledb + (size_t)(row0 + mrow) * H);
    const short8* w1h = reinterpret_cast<const short8*>(Wfc1);
    const short8* w2h = reinterpret_cast<const short8*>(Wfc2);
    const short8* w3h = reinterpret_cast<const short8*>(Wfc3);
    const short8* yv = reinterpret_cast<const short8*>(ylds);

    // ---- layer A: y1 = relu(x@c1 * sA + bA), K=128, N=128 ----
    f32x4 acc[8] = {};
#pragma unroll
    for (int kc = 0; kc < 4; kc++) {
        const short8 a = ar[kc * 4 + quad];
#pragma unroll
        for (int nt = 0; nt < 8; nt++) {
            const short8 bf = w1h[(kc * 8 + nt) * 64 + lane];
            acc[nt] = __builtin_amdgcn_mfma_f32_16x16x32_bf16(a, bf, acc[nt], 0, 0, 0);
        }
    }
#pragma unroll
    for (int nt = 0; nt < 8; nt++) {
        const int n = nt * 16 + mrow;
        const float sc = scbiH[0 * 128 + n];
        const float bi = scbiH[1 * 128 + n];
#pragma unroll
        for (int r = 0; r < 4; r++) {
            const float z = fmaxf(acc[nt][r] * sc + bi, 0.0f);
            ylds[(quad * 4 + r) * YSTR + n] = f2bf(z);
        }
    }

    // ---- layer B: y2 = relu(y1@c2 * sB + bB) ----
#pragma unroll
    for (int nt = 0; nt < 8; nt++) acc[nt] = (f32x4){0.f, 0.f, 0.f, 0.f};
#pragma unroll
    for (int kc = 0; kc < 4; kc++) {
        const short8 a = yv[mrow * (YSTR / 8) + kc * 4 + quad];
#pragma unroll
        for (int nt = 0; nt < 8; nt++) {
            const short8 bf = w2h[(kc * 8 + nt) * 64 + lane];
            acc[nt] = __builtin_amdgcn_mfma_f32_16x16x32_bf16(a, bf, acc[nt], 0, 0, 0);
        }
    }
#pragma unroll
    for (int nt = 0; nt < 8; nt++) {
        const int n = nt * 16 + mrow;
        const float sc = scbiH[2 * 128 + n];
        const float bi = scbiH[3 * 128 + n];
#pragma unroll
        for (int r = 0; r < 4; r++) {
            const float z = fmaxf(acc[nt][r] * sc + bi, 0.0f);
            ylds[(quad * 4 + r) * YSTR + n] = f2bf(z);
        }
    }

    // ---- layer C: net = y2@c3 + c3b, N=80 (cols 79 = pad) ----
    f32x4 acc3[5] = {};
#pragma unroll
    for (int kc = 0; kc < 4; kc++) {
        const short8 a = yv[mrow * (YSTR / 8) + kc * 4 + quad];
#pragma unroll
        for (int nt = 0; nt < 5; nt++) {
            const short8 bf = w3h[(kc * 5 + nt) * 64 + lane];
            acc3[nt] = __builtin_amdgcn_mfma_f32_16x16x32_bf16(a, bf, acc3[nt], 0, 0, 0);
        }
    }
#pragma unroll
    for (int nt = 0; nt < 5; nt++) {
        const int n = nt * 16 + mrow;
        const float bi = scbiH[512 + n];
#pragma unroll
        for (int r = 0; r < 4; r++)
            flds[(quad * 4 + r) * 84 + n] = acc3[nt][r] + bi;
    }

    // ---- fused decode: 16 rows x 124 cols, coalesced stores ----
    for (int m = 0; m < 16; m++) {
        const int row = row0 + m;
        const float* net = &flds[m * 84];
        const float* nz = new_xyz + (size_t)row * 3;
#pragma unroll
        for (int jj = 0; jj < 2; jj++) {
            const int j = lane + jj * 64;
            if (j < ODIM) {
                float val;
                if (j < 3) val = nz[j];
                else if (j < 5) val = net[j - 3];
                else if (j < 8) val = nz[j - 5] + net[2 + (j - 5)];
                else if (j < 20) val = net[5 + (j - 8)];
                else if (j < 32) val = net[17 + (j - 20)];
                else if (j < 44) val = net[17 + (j - 32)] * (float)(3.14159265358979323846 / 12.0);
                else if (j < 54) val = net[29 + (j - 44)];
                else if (j < 84) val = net[39 + (j - 54)];
                else if (j < 114) val = net[39 + (j - 84)] * MEANF[j - 84];
                else val = net[69 + (j - 114)];
                out[(size_t)row * ODIM + j] = val;
            }
        }
    }
}

extern "C" void kernel_launch(void* const* d_in, const int* in_sizes, int n_in,
                              void* d_out, int out_size, void* d_ws, size_t ws_size,
                              hipStream_t stream) {
    (void)in_sizes; (void)n_in; (void)out_size; (void)ws_size;
    const float* xyz = (const float*)d_in[0];
    const float* features = (const float*)d_in[1];
    const float* w0 = (const float*)d_in[2];
    const float* bb0 = (const float*)d_in[3];
    const float* g0 = (const float*)d_in[4];
    const float* be0 = (const float*)d_in[5];
    const float* m0 = (const float*)d_in[6];
    const float* v0 = (const float*)d_in[7];
    const float* w1 = (const float*)d_in[8];
    const float* bb1 = (const float*)d_in[9];
    const float* g1 = (const float*)d_in[10];
    const float* be1 = (const float*)d_in[11];
    const float* m1 = (const float*)d_in[12];
    const float* v1 = (const float*)d_in[13];
    const float* w2 = (const float*)d_in[14];
    const float* bb2 = (const float*)d_in[15];
    const float* g2 = (const float*)d_in[16];
    const float* be2 = (const float*)d_in[17];
    const float* m2 = (const float*)d_in[18];
    const float* v2 = (const float*)d_in[19];
    const float* c1w = (const float*)d_in[20];
    const float* c1b = (const float*)d_in[21];
    const float* g3 = (const float*)d_in[22];
    const float* be3 = (const float*)d_in[23];
    const float* m3 = (const float*)d_in[24];
    const float* v3 = (const float*)d_in[25];
    const float* c2w = (const float*)d_in[26];
    const float* c2b = (const float*)d_in[27];
    const float* g4 = (const float*)d_in[28];
    const float* be4 = (const float*)d_in[29];
    const float* m4 = (const float*)d_in[30];
    const float* v4 = (const float*)d_in[31];
    const float* c3w = (const float*)d_in[32];
    const float* c3b = (const float*)d_in[33];
    float* out = (float*)d_out;

    // workspace layout (byte offsets, 16B aligned)
    char* ws = (char*)d_ws;
    float* nxyz = (float*)(ws + 0);                            // 12288 f32   -> 49152
    float* scbi = (float*)(ws + 49152);                        // 768 f32     -> 52224
    float* scbiH = (float*)(ws + 52224);                       // 592 f32     -> 54592
    unsigned short* Wf0 = (unsigned short*)(ws + 54592);       // 36864 bf    -> 128320
    unsigned short* Wf1 = (unsigned short*)(ws + 128320);      // 16384 bf    -> 161088
    unsigned short* Wf2 = (unsigned short*)(ws + 161088);      // 16384 bf    -> 193856
    unsigned short* Wfc1 = (unsigned short*)(ws + 193856);     // 16384 bf    -> 226624
    unsigned short* Wfc2 = (unsigned short*)(ws + 226624);     // 16384 bf    -> 259392
    unsigned short* Wfc3 = (unsigned short*)(ws + 259392);     // 10240 bf    -> 279872
    unsigned short* pooledb = (unsigned short*)(ws + 279872);  // 524288 bf   -> 804160
    unsigned short* featT = (unsigned short*)(ws + 804160);    // 32*2048*256 bf16

    hipLaunchKernelGGL(prep_kernel, dim3(18), dim3(256), 0, stream,
                       w0, bb0, g0, be0, m0, v0,
                       w1, bb1, g1, be1, m1, v1,
                       w2, bb2, g2, be2, m2, v2,
                       c1w, c1b, g3, be3, m3, v3,
                       c2w, c2b, g4, be4, m4, v4,
                       c3w, c3b,
                       Wf0, Wf1, Wf2, Wfc1, Wfc2, Wfc3, scbi, scbiH);
    hipLaunchKernelGGL(fps_transpose_kernel, dim3(Bn + Bn * 256), dim3(256), 0, stream,
                       xyz, features, nxyz, featT);
    hipLaunchKernelGGL(groupmlp_mfma_kernel, dim3(Bn * Sn / 4), dim3(256), 0, stream,
                       xyz, featT, nxyz, Wf0, Wf1, Wf2, scbi, pooledb);
    hipLaunchKernelGGL(head_mfma_kernel, dim3(Bn * Sn / 16), dim3(64), 0, stream,
                       pooledb, nxyz, Wfc1, Wfc2, Wfc3, scbiH, out);
}